// Round 1
// baseline (5241.791 us; speedup 1.0000x reference)
//
#include <hip/hip_runtime.h>
#include <hip/hip_bf16.h>

// Decoder: B=32, S=128, H=256, V=32000, T=100
#define Bn 32
#define Sn 128
#define Hn 256
#define Vn 32000
#define Tn 100
#define GIn 768   // 3H

typedef __attribute__((ext_vector_type(8))) short bf16x8;
typedef __attribute__((ext_vector_type(4))) float f32x4;

__device__ __forceinline__ float frcp(float x){ return __builtin_amdgcn_rcpf(x); }
__device__ __forceinline__ float ftanh(float x){ return 1.0f - 2.0f*frcp(__expf(2.0f*x)+1.0f); }
__device__ __forceinline__ float fsigm(float x){ return frcp(1.0f + __expf(-x)); }

// ---------------- prep kernels (step-invariant hoisting) ----------------

// enc_k[b,s,:] = enc_outputs[b,s,:] @ Kw.T + Kb
__global__ __launch_bounds__(256) void k_enc(const float* __restrict__ enc_outputs,
    const float* __restrict__ Kw, const float* __restrict__ Kb, float* __restrict__ enc_k)
{
  const int bs = blockIdx.x, j = threadIdx.x;
  __shared__ __align__(16) float row[Hn];
  row[j] = enc_outputs[(size_t)bs*Hn + j];
  __syncthreads();
  const float* wr = Kw + (size_t)j*Hn;
  float a0 = 0.f, a1 = 0.f;
  #pragma unroll 4
  for(int k = 0; k < Hn; k += 8){
    float4 w0 = *(const float4*)(wr + k);
    float4 w1 = *(const float4*)(wr + k + 4);
    a0 = fmaf(row[k+0], w0.x, a0); a0 = fmaf(row[k+1], w0.y, a0);
    a0 = fmaf(row[k+2], w0.z, a0); a0 = fmaf(row[k+3], w0.w, a0);
    a1 = fmaf(row[k+4], w1.x, a1); a1 = fmaf(row[k+5], w1.y, a1);
    a1 = fmaf(row[k+6], w1.z, a1); a1 = fmaf(row[k+7], w1.w, a1);
  }
  enc_k[(size_t)bs*Hn + j] = a0 + a1 + Kb[j];
}

// encW2[b,s,j] = sum_d enc_outputs[b,s,d] * W_ih[j, 256+d]   (j<768)
__global__ __launch_bounds__(256) void k_encW2(const float* __restrict__ enc_outputs,
    const float* __restrict__ W_ih, float* __restrict__ encW2)
{
  const int bs = blockIdx.x, j = threadIdx.x;
  __shared__ __align__(16) float row[Hn];
  row[j] = enc_outputs[(size_t)bs*Hn + j];
  __syncthreads();
  #pragma unroll
  for(int r = 0; r < 3; r++){
    const int jj = j + r*Hn;
    const float* wr = W_ih + (size_t)jj*(2*Hn) + Hn;
    float a0 = 0.f, a1 = 0.f;
    #pragma unroll 4
    for(int k = 0; k < Hn; k += 8){
      float4 w0 = *(const float4*)(wr + k);
      float4 w1 = *(const float4*)(wr + k + 4);
      a0 = fmaf(row[k+0], w0.x, a0); a0 = fmaf(row[k+1], w0.y, a0);
      a0 = fmaf(row[k+2], w0.z, a0); a0 = fmaf(row[k+3], w0.w, a0);
      a1 = fmaf(row[k+4], w1.x, a1); a1 = fmaf(row[k+5], w1.y, a1);
      a1 = fmaf(row[k+6], w1.z, a1); a1 = fmaf(row[k+7], w1.w, a1);
    }
    encW2[(size_t)bs*GIn + jj] = a0 + a1;
  }
}

// gi_emb[t,b,j] = emb(token[t,b]) @ W_ih[j, :256].T + b_ih[j]
__global__ __launch_bounds__(256) void k_giemb(const int* __restrict__ target,
    const float* __restrict__ embedding, const float* __restrict__ W_ih,
    const float* __restrict__ b_ih, float* __restrict__ gi_emb)
{
  const int blk = blockIdx.x;            // t*32 + b
  const int t = blk >> 5, b = blk & 31;
  const int j = threadIdx.x;
  const int tok = (t == 0) ? 0 : target[b*Tn + (t-1)];
  __shared__ __align__(16) float row[Hn];
  row[j] = embedding[(size_t)tok*Hn + j];
  __syncthreads();
  #pragma unroll
  for(int r = 0; r < 3; r++){
    const int jj = j + r*Hn;
    const float* wr = W_ih + (size_t)jj*(2*Hn);
    float a0 = 0.f, a1 = 0.f;
    #pragma unroll 4
    for(int k = 0; k < Hn; k += 8){
      float4 w0 = *(const float4*)(wr + k);
      float4 w1 = *(const float4*)(wr + k + 4);
      a0 = fmaf(row[k+0], w0.x, a0); a0 = fmaf(row[k+1], w0.y, a0);
      a0 = fmaf(row[k+2], w0.z, a0); a0 = fmaf(row[k+3], w0.w, a0);
      a1 = fmaf(row[k+4], w1.x, a1); a1 = fmaf(row[k+5], w1.y, a1);
      a1 = fmaf(row[k+6], w1.z, a1); a1 = fmaf(row[k+7], w1.w, a1);
    }
    gi_emb[(size_t)blk*GIn + jj] = a0 + a1 + b_ih[jj];
  }
}

// f32 -> bf16 conversion (out_w)
__global__ __launch_bounds__(256) void k_cvt(const float* __restrict__ src,
    __hip_bfloat16* __restrict__ dst, int n)
{
  int i = (blockIdx.x*256 + threadIdx.x)*4;
  if(i < n){
    float4 v = *(const float4*)(src + i);
    dst[i+0] = __float2bfloat16(v.x);
    dst[i+1] = __float2bfloat16(v.y);
    dst[i+2] = __float2bfloat16(v.z);
    dst[i+3] = __float2bfloat16(v.w);
  }
}

// ---------------- the serial recurrence: one launch, t-loop inside ----------------
// 32 blocks (one per batch row), 1024 threads. All f32.
__global__ __launch_bounds__(1024) void k_loop(
    const float* __restrict__ enc_hidden,
    const float* __restrict__ enc_k,
    const float* __restrict__ encW2,
    const float* __restrict__ Qw, const float* __restrict__ Qb,
    const float* __restrict__ W_hh, const float* __restrict__ b_hh,
    const float* __restrict__ Vw, const float* __restrict__ Vb,
    const float* __restrict__ gi_emb,
    __hip_bfloat16* __restrict__ h_all,
    float* __restrict__ atts_out,
    float* __restrict__ hfin_out)
{
  const int b = blockIdx.x;
  const int tid = threadIdx.x;
  __shared__ __align__(16) float h_sh[Hn];
  __shared__ __align__(16) float q_sh[Hn];
  __shared__ __align__(16) float gh_sh[GIn];
  __shared__ __align__(16) float sc_sh[Sn];
  __shared__ __align__(16) float w_sh[Sn];
  __shared__ __align__(16) float gic_sh[GIn];

  if(tid < Hn) h_sh[tid] = enc_hidden[b*Hn + tid];
  __syncthreads();

  const int s_idx = tid >> 3, g = tid & 7;
  const float* ek_row = enc_k + ((size_t)b*Sn + s_idx)*Hn;
  const float* ew_col = encW2 + (size_t)b*Sn*GIn + tid;  // valid when tid<768
  const float vb0 = Vb[0];

  // per-thread phase-1 row: [Qw ; W_hh], 1024 output rows total
  const float* wrow = (tid < Hn) ? (Qw + (size_t)tid*Hn) : (W_hh + (size_t)(tid-Hn)*Hn);
  const float bias1 = (tid < Hn) ? Qb[tid] : b_hh[tid-Hn];

  for(int t = 0; t < Tn; t++){
    // ---- phase 1: [q | gh] = h @ [Qw ; W_hh].T + [Qb ; b_hh] ----
    {
      float a0 = 0.f, a1 = 0.f;
      #pragma unroll 4
      for(int k = 0; k < Hn; k += 8){
        float4 w0 = *(const float4*)(wrow + k);
        float4 w1 = *(const float4*)(wrow + k + 4);
        float4 h0 = *(const float4*)(&h_sh[k]);
        float4 h1 = *(const float4*)(&h_sh[k+4]);
        a0 = fmaf(h0.x, w0.x, a0); a0 = fmaf(h0.y, w0.y, a0);
        a0 = fmaf(h0.z, w0.z, a0); a0 = fmaf(h0.w, w0.w, a0);
        a1 = fmaf(h1.x, w1.x, a1); a1 = fmaf(h1.y, w1.y, a1);
        a1 = fmaf(h1.z, w1.z, a1); a1 = fmaf(h1.w, w1.w, a1);
      }
      float acc = a0 + a1 + bias1;
      if(tid < Hn) q_sh[tid] = acc; else gh_sh[tid - Hn] = acc;
    }
    __syncthreads();

    // ---- phase 2: scores[s] = Vb + sum_h Vw[h]*tanh(q[h]+enc_k[b,s,h]) ----
    {
      float p = 0.f;
      #pragma unroll 2
      for(int i = 0; i < 8; i++){
        const int k = i*32 + g*4;
        float4 q4 = *(const float4*)(&q_sh[k]);
        float4 e4 = *(const float4*)(ek_row + k);
        float4 v4 = *(const float4*)(Vw + k);
        p = fmaf(v4.x, ftanh(q4.x + e4.x), p);
        p = fmaf(v4.y, ftanh(q4.y + e4.y), p);
        p = fmaf(v4.z, ftanh(q4.z + e4.z), p);
        p = fmaf(v4.w, ftanh(q4.w + e4.w), p);
      }
      p += __shfl_xor(p, 1); p += __shfl_xor(p, 2); p += __shfl_xor(p, 4);
      if(g == 0) sc_sh[s_idx] = p + vb0;
    }
    __syncthreads();

    // ---- softmax over S=128 (wave 0) + write atts ----
    if(tid < 64){
      float v0 = sc_sh[tid], v1 = sc_sh[tid + 64];
      float m = fmaxf(v0, v1);
      #pragma unroll
      for(int off = 1; off < 64; off <<= 1) m = fmaxf(m, __shfl_xor(m, off));
      float e0 = __expf(v0 - m), e1 = __expf(v1 - m);
      float sm = e0 + e1;
      #pragma unroll
      for(int off = 1; off < 64; off <<= 1) sm += __shfl_xor(sm, off);
      float inv = frcp(sm);
      float w0 = e0*inv, w1 = e1*inv;
      w_sh[tid] = w0; w_sh[tid + 64] = w1;
      float* ao = atts_out + ((size_t)b*Tn + t)*Sn;
      ao[tid] = w0; ao[tid + 64] = w1;
    }
    __syncthreads();

    // ---- phase 3: gi_ctx[j] = sum_s w[s] * encW2[b,s,j] ----
    if(tid < GIn){
      float a0 = 0.f, a1 = 0.f;
      #pragma unroll 4
      for(int s2 = 0; s2 < Sn; s2 += 4){
        float4 wv = *(const float4*)(&w_sh[s2]);
        a0 = fmaf(wv.x, ew_col[(size_t)(s2+0)*GIn], a0);
        a1 = fmaf(wv.y, ew_col[(size_t)(s2+1)*GIn], a1);
        a0 = fmaf(wv.z, ew_col[(size_t)(s2+2)*GIn], a0);
        a1 = fmaf(wv.w, ew_col[(size_t)(s2+3)*GIn], a1);
      }
      gic_sh[tid] = a0 + a1;
    }
    __syncthreads();

    // ---- phase 4: GRU cell ----
    if(tid < Hn){
      const float* ge = gi_emb + ((size_t)t*Bn + b)*GIn;
      float gr = ge[tid]        + gic_sh[tid];
      float gz = ge[Hn + tid]   + gic_sh[Hn + tid];
      float gn = ge[2*Hn + tid] + gic_sh[2*Hn + tid];
      float r = fsigm(gr + gh_sh[tid]);
      float z = fsigm(gz + gh_sh[Hn + tid]);
      float n = ftanh(gn + r*gh_sh[2*Hn + tid]);
      float hold = h_sh[tid];
      float hn = (1.0f - z)*n + z*hold;
      h_all[((size_t)t*Bn + b)*Hn + tid] = __float2bfloat16(hn);
      if(t == Tn-1) hfin_out[b*Hn + tid] = hn;
      h_sh[tid] = hn;
    }
    __syncthreads();
  }
}

// ---------------- deferred logits GEMM (bf16 MFMA) + log_softmax ----------------
// C(3200x32000) = h_all(3200x256) @ out_w(32000x256)^T ; 2 passes (partials, final).
__global__ __launch_bounds__(256) void k_logits(
    const short* __restrict__ h_all, const short* __restrict__ w_bf,
    const float* __restrict__ out_b,
    float* __restrict__ pmax, float* __restrict__ psum,
    const float* __restrict__ lse, float* __restrict__ dec_out,
    int pass)
{
  const int tid = threadIdx.x;
  const int wave = tid >> 6, lane = tid & 63;
  const int lr = lane & 15, lg = lane >> 4;
  const int n0 = blockIdx.x * 64;
  const int m0 = blockIdx.y * 64 + wave * 16;
  const short* aptr = h_all + (size_t)(m0 + lr)*Hn + lg*8;
  const short* bptr = w_bf  + (size_t)(n0 + lr)*Hn + lg*8;
  f32x4 acc0 = {0.f,0.f,0.f,0.f}, acc1 = {0.f,0.f,0.f,0.f};
  f32x4 acc2 = {0.f,0.f,0.f,0.f}, acc3 = {0.f,0.f,0.f,0.f};
  #pragma unroll
  for(int kk = 0; kk < 8; kk++){
    bf16x8 a  = *(const bf16x8*)(aptr + kk*32);
    bf16x8 b0 = *(const bf16x8*)(bptr + 0*16*Hn + kk*32);
    bf16x8 b1 = *(const bf16x8*)(bptr + 1*16*Hn + kk*32);
    bf16x8 b2 = *(const bf16x8*)(bptr + 2*16*Hn + kk*32);
    bf16x8 b3 = *(const bf16x8*)(bptr + 3*16*Hn + kk*32);
    acc0 = __builtin_amdgcn_mfma_f32_16x16x32_bf16(a, b0, acc0, 0, 0, 0);
    acc1 = __builtin_amdgcn_mfma_f32_16x16x32_bf16(a, b1, acc1, 0, 0, 0);
    acc2 = __builtin_amdgcn_mfma_f32_16x16x32_bf16(a, b2, acc2, 0, 0, 0);
    acc3 = __builtin_amdgcn_mfma_f32_16x16x32_bf16(a, b3, acc3, 0, 0, 0);
  }
  const float bias0 = out_b[n0 +  0 + lr];
  const float bias1 = out_b[n0 + 16 + lr];
  const float bias2 = out_b[n0 + 32 + lr];
  const float bias3 = out_b[n0 + 48 + lr];
  if(pass == 0){
    #pragma unroll
    for(int i = 0; i < 4; i++){
      float v0 = acc0[i] + bias0, v1 = acc1[i] + bias1;
      float v2 = acc2[i] + bias2, v3 = acc3[i] + bias3;
      float m = fmaxf(fmaxf(v0, v1), fmaxf(v2, v3));
      m = fmaxf(m, __shfl_xor(m, 1)); m = fmaxf(m, __shfl_xor(m, 2));
      m = fmaxf(m, __shfl_xor(m, 4)); m = fmaxf(m, __shfl_xor(m, 8));
      float s = __expf(v0 - m) + __expf(v1 - m) + __expf(v2 - m) + __expf(v3 - m);
      s += __shfl_xor(s, 1); s += __shfl_xor(s, 2);
      s += __shfl_xor(s, 4); s += __shfl_xor(s, 8);
      if(lr == 0){
        const int row = m0 + lg*4 + i;
        pmax[(size_t)blockIdx.x*3200 + row] = m;
        psum[(size_t)blockIdx.x*3200 + row] = s;
      }
    }
  } else {
    #pragma unroll
    for(int i = 0; i < 4; i++){
      const int row = m0 + lg*4 + i;
      const float l = lse[row];
      const int bb = row & 31, tt = row >> 5;
      float* dst = dec_out + (size_t)bb*((size_t)Tn*Vn) + (size_t)tt*Vn + n0;
      dst[ 0 + lr] = acc0[i] + bias0 - l;
      dst[16 + lr] = acc1[i] + bias1 - l;
      dst[32 + lr] = acc2[i] + bias2 - l;
      dst[48 + lr] = acc3[i] + bias3 - l;
    }
  }
}

__global__ __launch_bounds__(256) void k_lse(const float* __restrict__ pmax,
    const float* __restrict__ psum, float* __restrict__ lse)
{
  const int row = blockIdx.x*256 + threadIdx.x;
  if(row >= Tn*Bn) return;
  float m = -3.0e38f;
  for(int c = 0; c < Vn/64; c++) m = fmaxf(m, pmax[(size_t)c*3200 + row]);
  float s = 0.f;
  for(int c = 0; c < Vn/64; c++)
    s += psum[(size_t)c*3200 + row] * __expf(pmax[(size_t)c*3200 + row] - m);
  lse[row] = m + __logf(s);
}

// ---------------- launch ----------------
extern "C" void kernel_launch(void* const* d_in, const int* in_sizes, int n_in,
                              void* d_out, int out_size, void* d_ws, size_t ws_size,
                              hipStream_t stream)
{
  const float* enc_outputs = (const float*)d_in[0];
  const float* enc_hidden  = (const float*)d_in[1];
  const int*   target      = (const int*)d_in[2];
  const float* embedding   = (const float*)d_in[3];
  const float* Qw   = (const float*)d_in[4];
  const float* Qb   = (const float*)d_in[5];
  const float* Kw   = (const float*)d_in[6];
  const float* Kb   = (const float*)d_in[7];
  const float* Vw   = (const float*)d_in[8];
  const float* Vb   = (const float*)d_in[9];
  const float* W_ih = (const float*)d_in[10];
  const float* W_hh = (const float*)d_in[11];
  const float* b_ih = (const float*)d_in[12];
  const float* b_hh = (const float*)d_in[13];
  const float* out_w = (const float*)d_in[14];
  const float* out_b = (const float*)d_in[15];

  float* dec  = (float*)d_out;                       // (B,T,V)
  float* hfin = dec + (size_t)Bn*Tn*Vn;              // (1,B,H)
  float* atts = hfin + Bn*Hn;                        // (B,T,S)

  // Step-invariant scratch lives inside the dec region of d_out: it is fully
  // consumed before k_logits pass 1 overwrites every element of dec.
  float* enc_k  = dec;                               // 1,048,576 f32
  float* encW2  = dec + 1048576;                     // 3,145,728 f32
  float* gi_emb = dec + 4194304;                     // 2,457,600 f32
  float* pmax   = dec + 6651904;                     // 1,600,000 f32
  float* psum   = dec + 8251904;                     // 1,600,000 f32 (end 9,851,904 < 102.4M)

  // ws: lse(3200 f32) + h_all(819200 bf16) + out_w bf16(8,192,000 bf16) ~= 18 MB
  float* wsf = (float*)d_ws;
  float* lse = wsf;
  __hip_bfloat16* h_all = (__hip_bfloat16*)(wsf + 3200);
  __hip_bfloat16* w_bf  = h_all + (size_t)Tn*Bn*Hn;

  k_enc  <<<dim3(Bn*Sn), dim3(256), 0, stream>>>(enc_outputs, Kw, Kb, enc_k);
  k_encW2<<<dim3(Bn*Sn), dim3(256), 0, stream>>>(enc_outputs, W_ih, encW2);
  k_giemb<<<dim3(Tn*Bn), dim3(256), 0, stream>>>(target, embedding, W_ih, b_ih, gi_emb);
  k_cvt  <<<dim3((Vn*Hn)/1024), dim3(256), 0, stream>>>(out_w, w_bf, Vn*Hn);

  k_loop <<<dim3(Bn), dim3(1024), 0, stream>>>(enc_hidden, enc_k, encW2,
            Qw, Qb, W_hh, b_hh, Vw, Vb, gi_emb, h_all, atts, hfin);

  k_logits<<<dim3(Vn/64, (Tn*Bn)/64), dim3(256), 0, stream>>>(
            (const short*)h_all, (const short*)w_bf, out_b,
            pmax, psum, (const float*)nullptr, (float*)nullptr, 0);
  k_lse   <<<dim3(13), dim3(256), 0, stream>>>(pmax, psum, lse);
  k_logits<<<dim3(Vn/64, (Tn*Bn)/64), dim3(256), 0, stream>>>(
            (const short*)h_all, (const short*)w_bf, out_b,
            (float*)nullptr, (float*)nullptr, lse, dec, 1);
}

// Round 2
// 3443.032 us; speedup vs baseline: 1.5224x; 1.5224x over previous
//
#include <hip/hip_runtime.h>
#include <hip/hip_bf16.h>

// Decoder: B=32, S=128, H=256, V=32000, T=100
#define Bn 32
#define Sn 128
#define Hn 256
#define Vn 32000
#define Tn 100
#define GIn 768   // 3H

typedef __attribute__((ext_vector_type(8))) short bf16x8;
typedef __attribute__((ext_vector_type(4))) float f32x4;

__device__ __forceinline__ float frcp(float x){ return __builtin_amdgcn_rcpf(x); }
__device__ __forceinline__ float ftanh(float x){ return 1.0f - 2.0f*frcp(__expf(2.0f*x)+1.0f); }
__device__ __forceinline__ float fsigm(float x){ return frcp(1.0f + __expf(-x)); }
__device__ __forceinline__ float b2f(unsigned short u){
  unsigned int v = ((unsigned int)u) << 16; return __builtin_bit_cast(float, v);
}
__device__ __forceinline__ unsigned short f2bu(float f){ // RNE f32->bf16 bits
  unsigned int u = __builtin_bit_cast(unsigned int, f);
  u += 0x7FFFu + ((u >> 16) & 1u);
  return (unsigned short)(u >> 16);
}

// ---------------- generic 32x32 tiled transpose: out(CxR) = in(RxC)^T ----------------
__global__ __launch_bounds__(256) void k_tr(const float* __restrict__ in,
    float* __restrict__ out, int R, int C)
{
  __shared__ float tile[32][33];
  const int bx = blockIdx.x*32, by = blockIdx.y*32;
  const int tx = threadIdx.x & 31, ty = threadIdx.x >> 5;
  #pragma unroll
  for(int r = ty; r < 32; r += 8)
    if(by + r < R && bx + tx < C) tile[r][tx] = in[(size_t)(by + r)*C + bx + tx];
  __syncthreads();
  #pragma unroll
  for(int r = ty; r < 32; r += 8)
    if(bx + r < C && by + tx < R) out[(size_t)(bx + r)*R + by + tx] = tile[tx][r];
}

// ---------------- W1b16 = bf16 rows [Qw(256x256); W_hh(768x256)] ----------------
__global__ __launch_bounds__(256) void k_cvtW1(const float* __restrict__ Qw,
    const float* __restrict__ W_hh, unsigned short* __restrict__ W1b16)
{
  const int i = blockIdx.x*256 + threadIdx.x;   // 1024*256 = 262144 total
  float v = (i < 65536) ? Qw[i] : W_hh[i - 65536];
  W1b16[i] = f2bu(v);
}

// f32 -> bf16 (out_w)
__global__ __launch_bounds__(256) void k_cvt(const float* __restrict__ src,
    __hip_bfloat16* __restrict__ dst, int n)
{
  int i = (blockIdx.x*256 + threadIdx.x)*4;
  if(i < n){
    float4 v = *(const float4*)(src + i);
    dst[i+0] = __float2bfloat16(v.x);
    dst[i+1] = __float2bfloat16(v.y);
    dst[i+2] = __float2bfloat16(v.z);
    dst[i+3] = __float2bfloat16(v.w);
  }
}

// ---------------- enc_kb16[bs][j] = bf16( enc[bs,:]·KwT[:,j] + Kb[j] ) ----------------
// 256 blocks x 16 rows, 256 threads. encl layout [d][r] padded to 20 for bank spread.
__global__ __launch_bounds__(256) void k_enc2(const float* __restrict__ enc_outputs,
    const float* __restrict__ KwT, const float* __restrict__ Kb,
    unsigned short* __restrict__ enc_kb16)
{
  const int r0 = blockIdx.x*16, j = threadIdx.x;
  __shared__ __align__(16) float encl[Hn][20];
  #pragma unroll
  for(int r = 0; r < 16; r++) encl[j][r] = enc_outputs[(size_t)(r0 + r)*Hn + j];
  __syncthreads();
  float acc[16];
  #pragma unroll
  for(int r = 0; r < 16; r++) acc[r] = Kb[j];
  for(int d = 0; d < Hn; d++){
    const float wv = KwT[(size_t)d*Hn + j];
    const float4 e0 = *(const float4*)&encl[d][0];
    const float4 e1 = *(const float4*)&encl[d][4];
    const float4 e2 = *(const float4*)&encl[d][8];
    const float4 e3 = *(const float4*)&encl[d][12];
    acc[0]+=e0.x*wv; acc[1]+=e0.y*wv; acc[2]+=e0.z*wv; acc[3]+=e0.w*wv;
    acc[4]+=e1.x*wv; acc[5]+=e1.y*wv; acc[6]+=e1.z*wv; acc[7]+=e1.w*wv;
    acc[8]+=e2.x*wv; acc[9]+=e2.y*wv; acc[10]+=e2.z*wv; acc[11]+=e2.w*wv;
    acc[12]+=e3.x*wv; acc[13]+=e3.y*wv; acc[14]+=e3.z*wv; acc[15]+=e3.w*wv;
  }
  #pragma unroll
  for(int r = 0; r < 16; r++) enc_kb16[(size_t)(r0 + r)*Hn + j] = f2bu(acc[r]);
}

// ---------------- encW2b16[bs][j] = bf16( enc[bs,:]·W_ihT[256+:, j] ) j<768 ----------------
__global__ __launch_bounds__(768) void k_encW2b(const float* __restrict__ enc_outputs,
    const float* __restrict__ W_ihT, unsigned short* __restrict__ encW2b16)
{
  const int r0 = blockIdx.x*16, tid = threadIdx.x;
  __shared__ __align__(16) float encl[Hn][20];
  if(tid < Hn){
    #pragma unroll
    for(int r = 0; r < 16; r++) encl[tid][r] = enc_outputs[(size_t)(r0 + r)*Hn + tid];
  }
  __syncthreads();
  float acc[16];
  #pragma unroll
  for(int r = 0; r < 16; r++) acc[r] = 0.f;
  for(int d = 0; d < Hn; d++){
    const float wv = W_ihT[(size_t)(Hn + d)*GIn + tid];
    const float4 e0 = *(const float4*)&encl[d][0];
    const float4 e1 = *(const float4*)&encl[d][4];
    const float4 e2 = *(const float4*)&encl[d][8];
    const float4 e3 = *(const float4*)&encl[d][12];
    acc[0]+=e0.x*wv; acc[1]+=e0.y*wv; acc[2]+=e0.z*wv; acc[3]+=e0.w*wv;
    acc[4]+=e1.x*wv; acc[5]+=e1.y*wv; acc[6]+=e1.z*wv; acc[7]+=e1.w*wv;
    acc[8]+=e2.x*wv; acc[9]+=e2.y*wv; acc[10]+=e2.z*wv; acc[11]+=e2.w*wv;
    acc[12]+=e3.x*wv; acc[13]+=e3.y*wv; acc[14]+=e3.z*wv; acc[15]+=e3.w*wv;
  }
  #pragma unroll
  for(int r = 0; r < 16; r++) encW2b16[(size_t)(r0 + r)*GIn + tid] = f2bu(acc[r]);
}

// ---------------- gi_emb[t*32+b][j] = emb(tok)·W_ihT[:256, j] + b_ih[j]  (f32) ----------------
__global__ __launch_bounds__(768) void k_giemb2(const int* __restrict__ target,
    const float* __restrict__ embedding, const float* __restrict__ W_ihT,
    const float* __restrict__ b_ih, float* __restrict__ gi_emb)
{
  const int r0 = blockIdx.x*16, tid = threadIdx.x;
  __shared__ __align__(16) float embl[Hn][20];
  if(tid < Hn){
    #pragma unroll
    for(int r = 0; r < 16; r++){
      const int row = r0 + r;            // t*32+b
      const int t = row >> 5, b = row & 31;
      const int tok = (t == 0) ? 0 : target[b*Tn + (t-1)];
      embl[tid][r] = embedding[(size_t)tok*Hn + tid];
    }
  }
  __syncthreads();
  float acc[16];
  #pragma unroll
  for(int r = 0; r < 16; r++) acc[r] = b_ih[tid];
  for(int d = 0; d < Hn; d++){
    const float wv = W_ihT[(size_t)d*GIn + tid];
    const float4 e0 = *(const float4*)&embl[d][0];
    const float4 e1 = *(const float4*)&embl[d][4];
    const float4 e2 = *(const float4*)&embl[d][8];
    const float4 e3 = *(const float4*)&embl[d][12];
    acc[0]+=e0.x*wv; acc[1]+=e0.y*wv; acc[2]+=e0.z*wv; acc[3]+=e0.w*wv;
    acc[4]+=e1.x*wv; acc[5]+=e1.y*wv; acc[6]+=e1.z*wv; acc[7]+=e1.w*wv;
    acc[8]+=e2.x*wv; acc[9]+=e2.y*wv; acc[10]+=e2.z*wv; acc[11]+=e2.w*wv;
    acc[12]+=e3.x*wv; acc[13]+=e3.y*wv; acc[14]+=e3.z*wv; acc[15]+=e3.w*wv;
  }
  #pragma unroll
  for(int r = 0; r < 16; r++) gi_emb[(size_t)(r0 + r)*GIn + tid] = acc[r];
}

// ---------------- serial recurrence: 32 blocks x 512 threads, t-loop inside ----------------
// phase1 via MFMA 16x16x32_bf16 with row-replicated A=h[b]; weights streamed bf16.
__global__ __launch_bounds__(512) void k_loop2(
    const float* __restrict__ enc_hidden,
    const unsigned short* __restrict__ enc_kb16,   // (B,S,H) bf16
    const unsigned short* __restrict__ encW2b16,   // (B,S,3H) bf16
    const unsigned short* __restrict__ W1b16,      // (1024,256) bf16 [Qw;W_hh]
    const float* __restrict__ Qb, const float* __restrict__ b_hh,
    const float* __restrict__ Vw, const float* __restrict__ Vb,
    const float* __restrict__ gi_emb,              // (T*B,3H) f32
    __hip_bfloat16* __restrict__ h_all,
    float* __restrict__ atts_out,
    float* __restrict__ hfin_out)
{
  const int b = blockIdx.x;
  const int tid = threadIdx.x;
  const int lane = tid & 63, wv = tid >> 6;        // 8 waves
  const int lr = lane & 15, lg = lane >> 4;

  __shared__ __align__(16) float h_sh[Hn];
  __shared__ __align__(16) short h_b16[Hn];
  __shared__ __align__(16) float qgh_sh[1024];
  __shared__ __align__(16) float bias1_sh[1024];
  __shared__ __align__(16) float vw_sh[Hn];
  __shared__ __align__(16) float sc_sh[Sn];
  __shared__ __align__(16) float w_sh[Sn];
  __shared__ __align__(16) float gic_sh[GIn];

  for(int f = tid; f < 1024; f += 512)
    bias1_sh[f] = (f < Hn) ? Qb[f] : b_hh[f - Hn];
  if(tid < Hn){
    float hv = enc_hidden[b*Hn + tid];
    h_sh[tid] = hv; h_b16[tid] = (short)f2bu(hv);
    vw_sh[tid] = Vw[tid];
  }
  __syncthreads();
  const float vb0 = Vb[0];

  // phase-1 per-wave weight base: wave owns 128 features (8 tiles of 16)
  const int n0 = wv*128;
  const unsigned short* wbase = W1b16 + (size_t)(n0 + lr)*Hn + lg*8;
  // phase-2 mapping
  const int s2 = tid >> 2, g2 = tid & 3;
  const unsigned short* ek = enc_kb16 + (size_t)(b*Sn + s2)*Hn;

  for(int t = 0; t < Tn; t++){
    // ---- phase 1: qgh = h[b] @ [Qw;W_hh].T (bf16 MFMA, rows replicated) ----
    {
      f32x4 acc[8];
      #pragma unroll
      for(int tt = 0; tt < 8; tt++) acc[tt] = (f32x4){0.f,0.f,0.f,0.f};
      #pragma unroll
      for(int kk = 0; kk < 8; kk++){
        bf16x8 a = *(const bf16x8*)(h_b16 + kk*32 + lg*8);
        #pragma unroll
        for(int tt = 0; tt < 8; tt++){
          bf16x8 w = *(const bf16x8*)(wbase + (size_t)tt*16*Hn + kk*32);
          acc[tt] = __builtin_amdgcn_mfma_f32_16x16x32_bf16(a, w, acc[tt], 0, 0, 0);
        }
      }
      if(lane < 16){
        #pragma unroll
        for(int tt = 0; tt < 8; tt++){
          const int f = n0 + tt*16 + lane;
          qgh_sh[f] = acc[tt][0] + bias1_sh[f];
        }
      }
    }
    __syncthreads();

    // ---- phase 2: scores[s] = Vb + sum_h Vw[h]*tanh(q[h]+enc_k[b,s,h]) ----
    {
      float p = 0.f;
      #pragma unroll
      for(int i = 0; i < 8; i++){
        const int kb = i*32 + g2*8;
        bf16x8 e8 = *(const bf16x8*)(ek + kb);
        #pragma unroll
        for(int j = 0; j < 8; j++){
          float ev = b2f((unsigned short)e8[j]);
          p = fmaf(vw_sh[kb + j], ftanh(qgh_sh[kb + j] + ev), p);
        }
      }
      p += __shfl_xor(p, 1); p += __shfl_xor(p, 2);
      if(g2 == 0) sc_sh[s2] = p + vb0;
    }
    __syncthreads();

    // ---- softmax over S=128 (wave 0) + atts write ----
    if(tid < 64){
      float v0 = sc_sh[tid], v1 = sc_sh[tid + 64];
      float m = fmaxf(v0, v1);
      #pragma unroll
      for(int off = 1; off < 64; off <<= 1) m = fmaxf(m, __shfl_xor(m, off));
      float e0 = __expf(v0 - m), e1 = __expf(v1 - m);
      float sm = e0 + e1;
      #pragma unroll
      for(int off = 1; off < 64; off <<= 1) sm += __shfl_xor(sm, off);
      float inv = frcp(sm);
      float w0 = e0*inv, w1 = e1*inv;
      w_sh[tid] = w0; w_sh[tid + 64] = w1;
      float* ao = atts_out + ((size_t)b*Tn + t)*Sn;
      ao[tid] = w0; ao[tid + 64] = w1;
    }
    __syncthreads();

    // ---- phase 3: gi_ctx[j] = sum_s w[s]*encW2[b,s,j]  (bf16, 2 cols/thread) ----
    if(tid < 384){
      const int j = tid*2;
      const unsigned short* ew = encW2b16 + (size_t)b*Sn*GIn + j;
      float a0 = 0.f, a1 = 0.f;
      #pragma unroll 8
      for(int s = 0; s < Sn; s++){
        ushort2 u = *(const ushort2*)(ew + (size_t)s*GIn);
        float ws = w_sh[s];
        a0 = fmaf(ws, b2f(u.x), a0);
        a1 = fmaf(ws, b2f(u.y), a1);
      }
      gic_sh[j] = a0; gic_sh[j+1] = a1;
    }
    __syncthreads();

    // ---- phase 4: GRU cell (f32) ----
    if(tid < Hn){
      const float* ge = gi_emb + ((size_t)t*Bn + b)*GIn;
      float gr = ge[tid]        + gic_sh[tid];
      float gz = ge[Hn + tid]   + gic_sh[Hn + tid];
      float gn = ge[2*Hn + tid] + gic_sh[2*Hn + tid];
      float r = fsigm(gr + qgh_sh[256 + tid]);
      float z = fsigm(gz + qgh_sh[512 + tid]);
      float n = ftanh(gn + r*qgh_sh[768 + tid]);
      float hn2 = (1.0f - z)*n + z*h_sh[tid];
      h_all[((size_t)t*Bn + b)*Hn + tid] = __float2bfloat16(hn2);
      if(t == Tn-1) hfin_out[b*Hn + tid] = hn2;
      h_sh[tid] = hn2;
      h_b16[tid] = (short)f2bu(hn2);
    }
    __syncthreads();
  }
}

// ---------------- deferred logits GEMM (bf16 MFMA) + log_softmax ----------------
__global__ __launch_bounds__(256) void k_logits(
    const short* __restrict__ h_all, const short* __restrict__ w_bf,
    const float* __restrict__ out_b,
    float* __restrict__ pmax, float* __restrict__ psum,
    const float* __restrict__ lse, float* __restrict__ dec_out,
    int pass)
{
  const int tid = threadIdx.x;
  const int wave = tid >> 6, lane = tid & 63;
  const int lr = lane & 15, lg = lane >> 4;
  const int n0 = blockIdx.x * 64;
  const int m0 = blockIdx.y * 64 + wave * 16;
  const short* aptr = h_all + (size_t)(m0 + lr)*Hn + lg*8;
  const short* bptr = w_bf  + (size_t)(n0 + lr)*Hn + lg*8;
  f32x4 acc0 = {0.f,0.f,0.f,0.f}, acc1 = {0.f,0.f,0.f,0.f};
  f32x4 acc2 = {0.f,0.f,0.f,0.f}, acc3 = {0.f,0.f,0.f,0.f};
  #pragma unroll
  for(int kk = 0; kk < 8; kk++){
    bf16x8 a  = *(const bf16x8*)(aptr + kk*32);
    bf16x8 b0 = *(const bf16x8*)(bptr + 0*16*Hn + kk*32);
    bf16x8 b1 = *(const bf16x8*)(bptr + 1*16*Hn + kk*32);
    bf16x8 b2 = *(const bf16x8*)(bptr + 2*16*Hn + kk*32);
    bf16x8 b3 = *(const bf16x8*)(bptr + 3*16*Hn + kk*32);
    acc0 = __builtin_amdgcn_mfma_f32_16x16x32_bf16(a, b0, acc0, 0, 0, 0);
    acc1 = __builtin_amdgcn_mfma_f32_16x16x32_bf16(a, b1, acc1, 0, 0, 0);
    acc2 = __builtin_amdgcn_mfma_f32_16x16x32_bf16(a, b2, acc2, 0, 0, 0);
    acc3 = __builtin_amdgcn_mfma_f32_16x16x32_bf16(a, b3, acc3, 0, 0, 0);
  }
  const float bias0 = out_b[n0 +  0 + lr];
  const float bias1 = out_b[n0 + 16 + lr];
  const float bias2 = out_b[n0 + 32 + lr];
  const float bias3 = out_b[n0 + 48 + lr];
  if(pass == 0){
    #pragma unroll
    for(int i = 0; i < 4; i++){
      float v0 = acc0[i] + bias0, v1 = acc1[i] + bias1;
      float v2 = acc2[i] + bias2, v3 = acc3[i] + bias3;
      float m = fmaxf(fmaxf(v0, v1), fmaxf(v2, v3));
      m = fmaxf(m, __shfl_xor(m, 1)); m = fmaxf(m, __shfl_xor(m, 2));
      m = fmaxf(m, __shfl_xor(m, 4)); m = fmaxf(m, __shfl_xor(m, 8));
      float s = __expf(v0 - m) + __expf(v1 - m) + __expf(v2 - m) + __expf(v3 - m);
      s += __shfl_xor(s, 1); s += __shfl_xor(s, 2);
      s += __shfl_xor(s, 4); s += __shfl_xor(s, 8);
      if(lr == 0){
        const int row = m0 + lg*4 + i;
        pmax[(size_t)blockIdx.x*3200 + row] = m;
        psum[(size_t)blockIdx.x*3200 + row] = s;
      }
    }
  } else {
    #pragma unroll
    for(int i = 0; i < 4; i++){
      const int row = m0 + lg*4 + i;
      const float l = lse[row];
      const int bb = row & 31, tt = row >> 5;
      float* dst = dec_out + (size_t)bb*((size_t)Tn*Vn) + (size_t)tt*Vn + n0;
      dst[ 0 + lr] = acc0[i] + bias0 - l;
      dst[16 + lr] = acc1[i] + bias1 - l;
      dst[32 + lr] = acc2[i] + bias2 - l;
      dst[48 + lr] = acc3[i] + bias3 - l;
    }
  }
}

__global__ __launch_bounds__(256) void k_lse(const float* __restrict__ pmax,
    const float* __restrict__ psum, float* __restrict__ lse)
{
  const int row = blockIdx.x*256 + threadIdx.x;
  if(row >= Tn*Bn) return;
  float m = -3.0e38f;
  for(int c = 0; c < Vn/64; c++) m = fmaxf(m, pmax[(size_t)c*3200 + row]);
  float s = 0.f;
  for(int c = 0; c < Vn/64; c++)
    s += psum[(size_t)c*3200 + row] * __expf(pmax[(size_t)c*3200 + row] - m);
  lse[row] = m + __logf(s);
}

// ---------------- launch ----------------
extern "C" void kernel_launch(void* const* d_in, const int* in_sizes, int n_in,
                              void* d_out, int out_size, void* d_ws, size_t ws_size,
                              hipStream_t stream)
{
  const float* enc_outputs = (const float*)d_in[0];
  const float* enc_hidden  = (const float*)d_in[1];
  const int*   target      = (const int*)d_in[2];
  const float* embedding   = (const float*)d_in[3];
  const float* Qw   = (const float*)d_in[4];
  const float* Qb   = (const float*)d_in[5];
  const float* Kw   = (const float*)d_in[6];
  const float* Kb   = (const float*)d_in[7];
  const float* Vw   = (const float*)d_in[8];
  const float* Vb   = (const float*)d_in[9];
  const float* W_ih = (const float*)d_in[10];
  const float* W_hh = (const float*)d_in[11];
  const float* b_ih = (const float*)d_in[12];
  const float* b_hh = (const float*)d_in[13];
  const float* out_w = (const float*)d_in[14];
  const float* out_b = (const float*)d_in[15];

  float* dec  = (float*)d_out;                       // (B,T,V) = 102,400,000 f32
  float* hfin = dec + (size_t)Bn*Tn*Vn;              // (1,B,H)
  float* atts = hfin + Bn*Hn;                        // (B,T,S)

  // Scratch inside the dec region (fully consumed before the final pass
  // overwrites it; pmax/psum are at disjoint offsets):
  unsigned short* enc_kb16  = (unsigned short*)(dec);            // 1,048,576 bf16 = 524,288 f32 slots
  unsigned short* encW2b16  = (unsigned short*)(dec + 524288);   // 3,145,728 bf16 = 1,572,864 slots
  float* gi_emb = dec + 2097152;                                 // 2,457,600 f32
  float* W_ihT  = dec + 4554752;                                 // 393,216 f32
  float* KwT    = dec + 4947968;                                 // 65,536 f32
  float* pmax   = dec + 5013504;                                 // 1,600,000 f32
  float* psum   = dec + 6613504;                                 // 1,600,000 f32
  unsigned short* W1b16 = (unsigned short*)(dec + 8213504);      // 262,144 bf16 (ends 8,344,576)

  // ws: lse + h_all(bf16) + out_w(bf16)  (~18 MB, same as round 1)
  float* wsf = (float*)d_ws;
  float* lse = wsf;
  __hip_bfloat16* h_all = (__hip_bfloat16*)(wsf + 3200);
  __hip_bfloat16* w_bf  = h_all + (size_t)Tn*Bn*Hn;

  // prep
  k_tr    <<<dim3(8, 8),   dim3(256), 0, stream>>>(Kw, KwT, 256, 256);
  k_tr    <<<dim3(16, 24), dim3(256), 0, stream>>>(W_ih, W_ihT, 768, 512);
  k_cvtW1 <<<dim3(1024),   dim3(256), 0, stream>>>(Qw, W_hh, W1b16);
  k_cvt   <<<dim3((Vn*Hn)/1024), dim3(256), 0, stream>>>(out_w, w_bf, Vn*Hn);
  k_enc2  <<<dim3(256), dim3(256), 0, stream>>>(enc_outputs, KwT, Kb, enc_kb16);
  k_encW2b<<<dim3(256), dim3(768), 0, stream>>>(enc_outputs, W_ihT, encW2b16);
  k_giemb2<<<dim3(200), dim3(768), 0, stream>>>(target, embedding, W_ihT, b_ih, gi_emb);

  // recurrence
  k_loop2 <<<dim3(Bn), dim3(512), 0, stream>>>(enc_hidden, enc_kb16, encW2b16,
            W1b16, Qb, b_hh, Vw, Vb, gi_emb, h_all, atts, hfin);

  // logits + log_softmax
  k_logits<<<dim3(Vn/64, (Tn*Bn)/64), dim3(256), 0, stream>>>(
            (const short*)h_all, (const short*)w_bf, out_b,
            pmax, psum, (const float*)nullptr, (float*)nullptr, 0);
  k_lse   <<<dim3(13), dim3(256), 0, stream>>>(pmax, psum, lse);
  k_logits<<<dim3(Vn/64, (Tn*Bn)/64), dim3(256), 0, stream>>>(
            (const short*)h_all, (const short*)w_bf, out_b,
            (float*)nullptr, (float*)nullptr, lse, dec, 1);
}

// Round 3
// 3116.073 us; speedup vs baseline: 1.6822x; 1.1049x over previous
//
#include <hip/hip_runtime.h>
#include <hip/hip_bf16.h>

// Decoder: B=32, S=128, H=256, V=32000, T=100
#define Bn 32
#define Sn 128
#define Hn 256
#define Vn 32000
#define Tn 100
#define GIn 768   // 3H

typedef __attribute__((ext_vector_type(8))) short bf16x8;
typedef __attribute__((ext_vector_type(4))) float f32x4;

__device__ __forceinline__ float frcp(float x){ return __builtin_amdgcn_rcpf(x); }
__device__ __forceinline__ float ftanh(float x){ return 1.0f - 2.0f*frcp(__expf(2.0f*x)+1.0f); }
__device__ __forceinline__ float fsigm(float x){ return frcp(1.0f + __expf(-x)); }
__device__ __forceinline__ float b2f(unsigned short u){
  unsigned int v = ((unsigned int)u) << 16; return __builtin_bit_cast(float, v);
}
__device__ __forceinline__ unsigned short f2bu(float f){ // RNE f32->bf16 bits
  unsigned int u = __builtin_bit_cast(unsigned int, f);
  u += 0x7FFFu + ((u >> 16) & 1u);
  return (unsigned short)(u >> 16);
}

// ---------------- generic 32x32 tiled transpose: out(CxR) = in(RxC)^T ----------------
__global__ __launch_bounds__(256) void k_tr(const float* __restrict__ in,
    float* __restrict__ out, int R, int C)
{
  __shared__ float tile[32][33];
  const int bx = blockIdx.x*32, by = blockIdx.y*32;
  const int tx = threadIdx.x & 31, ty = threadIdx.x >> 5;
  #pragma unroll
  for(int r = ty; r < 32; r += 8)
    if(by + r < R && bx + tx < C) tile[r][tx] = in[(size_t)(by + r)*C + bx + tx];
  __syncthreads();
  #pragma unroll
  for(int r = ty; r < 32; r += 8)
    if(bx + r < C && by + tx < R) out[(size_t)(bx + r)*R + by + tx] = tile[tx][r];
}

// ---------------- W1P: [Qw;W_hh] bf16 packed in wave-linear consumption order ----
// dst element: gid*512 + l*8 + j  where gid = w*64 + kk*8 + tt, l = lane
// src: row f = w*128 + tt*16 + (l&15), col = kk*32 + (l>>4)*8 + j
__global__ __launch_bounds__(256) void k_packW1(const float* __restrict__ Qw,
    const float* __restrict__ Whh, unsigned short* __restrict__ W1P)
{
  const int tid = blockIdx.x*256 + threadIdx.x;   // 0..32767
  const int gid = tid >> 6;                       // 0..511
  const int l = tid & 63;
  const int w = gid >> 6, kk = (gid >> 3) & 7, tt = gid & 7;
  const int f = w*128 + tt*16 + (l & 15);
  const int col = kk*32 + (l >> 4)*8;
  const float* src = (f < 256 ? Qw + (size_t)f*Hn : Whh + (size_t)(f-256)*Hn) + col;
  float4 v0 = *(const float4*)src, v1 = *(const float4*)(src + 4);
  unsigned short* d = W1P + (size_t)gid*512 + l*8;
  d[0]=f2bu(v0.x); d[1]=f2bu(v0.y); d[2]=f2bu(v0.z); d[3]=f2bu(v0.w);
  d[4]=f2bu(v1.x); d[5]=f2bu(v1.y); d[6]=f2bu(v1.z); d[7]=f2bu(v1.w);
}

// f32 -> bf16 (out_w)
__global__ __launch_bounds__(256) void k_cvt(const float* __restrict__ src,
    __hip_bfloat16* __restrict__ dst, int n)
{
  int i = (blockIdx.x*256 + threadIdx.x)*4;
  if(i < n){
    float4 v = *(const float4*)(src + i);
    dst[i+0] = __float2bfloat16(v.x);
    dst[i+1] = __float2bfloat16(v.y);
    dst[i+2] = __float2bfloat16(v.z);
    dst[i+3] = __float2bfloat16(v.w);
  }
}

// ---------------- enc_kb16[bs][j] = bf16( enc[bs,:]·KwT[:,j] + Kb[j] ) ----------------
__global__ __launch_bounds__(256) void k_enc2(const float* __restrict__ enc_outputs,
    const float* __restrict__ KwT, const float* __restrict__ Kb,
    unsigned short* __restrict__ enc_kb16)
{
  const int r0 = blockIdx.x*16, j = threadIdx.x;
  __shared__ __align__(16) float encl[Hn][20];
  #pragma unroll
  for(int r = 0; r < 16; r++) encl[j][r] = enc_outputs[(size_t)(r0 + r)*Hn + j];
  __syncthreads();
  float acc[16];
  #pragma unroll
  for(int r = 0; r < 16; r++) acc[r] = Kb[j];
  for(int d = 0; d < Hn; d++){
    const float wv = KwT[(size_t)d*Hn + j];
    const float4 e0 = *(const float4*)&encl[d][0];
    const float4 e1 = *(const float4*)&encl[d][4];
    const float4 e2 = *(const float4*)&encl[d][8];
    const float4 e3 = *(const float4*)&encl[d][12];
    acc[0]+=e0.x*wv; acc[1]+=e0.y*wv; acc[2]+=e0.z*wv; acc[3]+=e0.w*wv;
    acc[4]+=e1.x*wv; acc[5]+=e1.y*wv; acc[6]+=e1.z*wv; acc[7]+=e1.w*wv;
    acc[8]+=e2.x*wv; acc[9]+=e2.y*wv; acc[10]+=e2.z*wv; acc[11]+=e2.w*wv;
    acc[12]+=e3.x*wv; acc[13]+=e3.y*wv; acc[14]+=e3.z*wv; acc[15]+=e3.w*wv;
  }
  #pragma unroll
  for(int r = 0; r < 16; r++) enc_kb16[(size_t)(r0 + r)*Hn + j] = f2bu(acc[r]);
}

// ---------------- ekP: enc_k permuted to phase-2 consumption order ----------------
// per b: octet o = g*64 + l (g = w*8+i): src s = w*16 + (l>>2), e0 = i*32 + (l&3)*8
__global__ __launch_bounds__(256) void k_packEk(const unsigned short* __restrict__ enc_kb16,
    unsigned short* __restrict__ ekP)
{
  const int tid = blockIdx.x*256 + threadIdx.x;   // 0..131071
  const int b = tid >> 12;
  const int o = tid & 4095;
  const int g = o >> 6, l = o & 63;
  const int w = g >> 3, i = g & 7;
  const int s = w*16 + (l >> 2);
  const int e0 = i*32 + (l & 3)*8;
  const int4 v = *(const int4*)(enc_kb16 + ((size_t)(b*Sn + s))*Hn + e0);
  *(int4*)(ekP + (size_t)b*32768 + (size_t)o*8) = v;
}

// ---------------- encW2b16[bs][j] = bf16( enc[bs,:]·W_ihT[256+:, j] ) j<768 ----------------
__global__ __launch_bounds__(768) void k_encW2b(const float* __restrict__ enc_outputs,
    const float* __restrict__ W_ihT, unsigned short* __restrict__ encW2b16)
{
  const int r0 = blockIdx.x*16, tid = threadIdx.x;
  __shared__ __align__(16) float encl[Hn][20];
  if(tid < Hn){
    #pragma unroll
    for(int r = 0; r < 16; r++) encl[tid][r] = enc_outputs[(size_t)(r0 + r)*Hn + tid];
  }
  __syncthreads();
  float acc[16];
  #pragma unroll
  for(int r = 0; r < 16; r++) acc[r] = 0.f;
  for(int d = 0; d < Hn; d++){
    const float wv = W_ihT[(size_t)(Hn + d)*GIn + tid];
    const float4 e0 = *(const float4*)&encl[d][0];
    const float4 e1 = *(const float4*)&encl[d][4];
    const float4 e2 = *(const float4*)&encl[d][8];
    const float4 e3 = *(const float4*)&encl[d][12];
    acc[0]+=e0.x*wv; acc[1]+=e0.y*wv; acc[2]+=e0.z*wv; acc[3]+=e0.w*wv;
    acc[4]+=e1.x*wv; acc[5]+=e1.y*wv; acc[6]+=e1.z*wv; acc[7]+=e1.w*wv;
    acc[8]+=e2.x*wv; acc[9]+=e2.y*wv; acc[10]+=e2.z*wv; acc[11]+=e2.w*wv;
    acc[12]+=e3.x*wv; acc[13]+=e3.y*wv; acc[14]+=e3.z*wv; acc[15]+=e3.w*wv;
  }
  #pragma unroll
  for(int r = 0; r < 16; r++) encW2b16[(size_t)(r0 + r)*GIn + tid] = f2bu(acc[r]);
}

// ---------------- gi_emb[t*32+b][j] = emb(tok)·W_ihT[:256, j] + b_ih[j]  (f32) ----------------
__global__ __launch_bounds__(768) void k_giemb2(const int* __restrict__ target,
    const float* __restrict__ embedding, const float* __restrict__ W_ihT,
    const float* __restrict__ b_ih, float* __restrict__ gi_emb)
{
  const int r0 = blockIdx.x*16, tid = threadIdx.x;
  __shared__ __align__(16) float embl[Hn][20];
  if(tid < Hn){
    #pragma unroll
    for(int r = 0; r < 16; r++){
      const int row = r0 + r;            // t*32+b
      const int t = row >> 5, b = row & 31;
      const int tok = (t == 0) ? 0 : target[b*Tn + (t-1)];
      embl[tid][r] = embedding[(size_t)tok*Hn + tid];
    }
  }
  __syncthreads();
  float acc[16];
  #pragma unroll
  for(int r = 0; r < 16; r++) acc[r] = b_ih[tid];
  for(int d = 0; d < Hn; d++){
    const float wv = W_ihT[(size_t)d*GIn + tid];
    const float4 e0 = *(const float4*)&embl[d][0];
    const float4 e1 = *(const float4*)&embl[d][4];
    const float4 e2 = *(const float4*)&embl[d][8];
    const float4 e3 = *(const float4*)&embl[d][12];
    acc[0]+=e0.x*wv; acc[1]+=e0.y*wv; acc[2]+=e0.z*wv; acc[3]+=e0.w*wv;
    acc[4]+=e1.x*wv; acc[5]+=e1.y*wv; acc[6]+=e1.z*wv; acc[7]+=e1.w*wv;
    acc[8]+=e2.x*wv; acc[9]+=e2.y*wv; acc[10]+=e2.z*wv; acc[11]+=e2.w*wv;
    acc[12]+=e3.x*wv; acc[13]+=e3.y*wv; acc[14]+=e3.z*wv; acc[15]+=e3.w*wv;
  }
  #pragma unroll
  for(int r = 0; r < 16; r++) gi_emb[(size_t)(r0 + r)*GIn + tid] = acc[r];
}

// ---------------- serial recurrence: 32 blocks x 512 threads, t-loop inside ----------------
// W1P streamed linearly per wave; enc_k LDS-resident (packed order); encW2 streamed linear.
__global__ __launch_bounds__(512) void k_loop3(
    const float* __restrict__ enc_hidden,
    const unsigned short* __restrict__ ekP,        // (B,32768) bf16 packed
    const unsigned short* __restrict__ encW2b16,   // (B,S,3H) bf16 (consumption-linear)
    const unsigned short* __restrict__ W1P,        // (512*512) bf16 packed
    const float* __restrict__ Qb, const float* __restrict__ b_hh,
    const float* __restrict__ Vw, const float* __restrict__ Vb,
    const float* __restrict__ gi_emb,              // (T*B,3H) f32
    __hip_bfloat16* __restrict__ h_all,
    float* __restrict__ atts_out,
    float* __restrict__ hfin_out)
{
  const int b = blockIdx.x;
  const int tid = threadIdx.x;
  const int lane = tid & 63, wv = tid >> 6;        // 8 waves
  const int lg = lane >> 4;

  __shared__ __align__(16) unsigned short ek_l[32768];  // 64KB, packed order
  __shared__ __align__(16) float h_sh[Hn];
  __shared__ __align__(16) short h_b16[Hn];
  __shared__ __align__(16) float qgh_sh[1024];
  __shared__ __align__(16) float vw_sh[Hn];
  __shared__ __align__(16) float sc_sh[Sn];
  __shared__ __align__(16) float w_sh[Sn];
  __shared__ __align__(16) float gic_sh[GIn];

  // stage ekP[b] into LDS (linear both sides)
  {
    const unsigned short* src = ekP + (size_t)b*32768;
    #pragma unroll
    for(int c = 0; c < 8; c++){
      const int idx = (c*512 + tid)*8;
      *(int4*)(ek_l + idx) = *(const int4*)(src + idx);
    }
  }
  // per-thread phase-1 bias (registers, used by lane<16 only)
  float bias_r[8];
  #pragma unroll
  for(int tt = 0; tt < 8; tt++){
    const int f = wv*128 + tt*16 + (lane & 15);
    bias_r[tt] = (f < Hn) ? Qb[f] : b_hh[f - Hn];
  }
  if(tid < Hn){
    float hv = enc_hidden[b*Hn + tid];
    h_sh[tid] = hv; h_b16[tid] = (short)f2bu(hv);
    vw_sh[tid] = Vw[tid];
  }
  __syncthreads();
  const float vb0 = Vb[0];

  const unsigned short* wbase = W1P + (size_t)wv*64*512 + lane*8;  // per-wave 64KB stream
  const int s2 = tid >> 2, g2 = tid & 3;
  const unsigned short* ew = encW2b16 + (size_t)b*Sn*GIn + tid*2;  // phase 3 (tid<384)

  for(int t = 0; t < Tn; t++){
    // ---- phase 1: qgh = h[b] @ [Qw;W_hh].T (bf16 MFMA, linear weight stream) ----
    {
      f32x4 acc[8];
      #pragma unroll
      for(int tt = 0; tt < 8; tt++) acc[tt] = (f32x4){0.f,0.f,0.f,0.f};
      #pragma unroll
      for(int kk = 0; kk < 8; kk++){
        bf16x8 a = *(const bf16x8*)(h_b16 + kk*32 + lg*8);
        #pragma unroll
        for(int tt = 0; tt < 8; tt++){
          bf16x8 w = *(const bf16x8*)(wbase + (size_t)((kk*8 + tt) << 9));
          acc[tt] = __builtin_amdgcn_mfma_f32_16x16x32_bf16(a, w, acc[tt], 0, 0, 0);
        }
      }
      if(lane < 16){
        #pragma unroll
        for(int tt = 0; tt < 8; tt++)
          qgh_sh[wv*128 + tt*16 + lane] = acc[tt][0] + bias_r[tt];
      }
    }
    __syncthreads();

    // ---- phase 2: scores[s] = Vb + sum_h Vw[h]*tanh(q[h]+enc_k[b,s,h]) (enc_k in LDS) ----
    {
      float p = 0.f;
      #pragma unroll
      for(int i = 0; i < 8; i++){
        bf16x8 e8 = *(const bf16x8*)(ek_l + ((wv*8 + i) << 9) + lane*8);
        const int kb = i*32 + g2*8;
        #pragma unroll
        for(int j = 0; j < 8; j++){
          float ev = b2f((unsigned short)e8[j]);
          p = fmaf(vw_sh[kb + j], ftanh(qgh_sh[kb + j] + ev), p);
        }
      }
      p += __shfl_xor(p, 1); p += __shfl_xor(p, 2);
      if(g2 == 0) sc_sh[s2] = p + vb0;
    }
    __syncthreads();

    // ---- softmax over S=128 (wave 0) + atts write ----
    if(tid < 64){
      float v0 = sc_sh[tid], v1 = sc_sh[tid + 64];
      float m = fmaxf(v0, v1);
      #pragma unroll
      for(int off = 1; off < 64; off <<= 1) m = fmaxf(m, __shfl_xor(m, off));
      float e0 = __expf(v0 - m), e1 = __expf(v1 - m);
      float sm = e0 + e1;
      #pragma unroll
      for(int off = 1; off < 64; off <<= 1) sm += __shfl_xor(sm, off);
      float inv = frcp(sm);
      float w0 = e0*inv, w1 = e1*inv;
      w_sh[tid] = w0; w_sh[tid + 64] = w1;
      float* ao = atts_out + ((size_t)b*Tn + t)*Sn;
      ao[tid] = w0; ao[tid + 64] = w1;
    }
    __syncthreads();

    // ---- phase 3: gi_ctx[j] = sum_s w[s]*encW2[b,s,j] (linear stream across 6 waves) ----
    if(tid < 384){
      const int j = tid*2;
      float a0 = 0.f, a1 = 0.f;
      #pragma unroll 8
      for(int s = 0; s < Sn; s++){
        ushort2 u = *(const ushort2*)(ew + (size_t)s*GIn);
        float ws = w_sh[s];
        a0 = fmaf(ws, b2f(u.x), a0);
        a1 = fmaf(ws, b2f(u.y), a1);
      }
      gic_sh[j] = a0; gic_sh[j+1] = a1;
    }
    __syncthreads();

    // ---- phase 4: GRU cell (f32) ----
    if(tid < Hn){
      const float* ge = gi_emb + ((size_t)t*Bn + b)*GIn;
      float gr = ge[tid]        + gic_sh[tid];
      float gz = ge[Hn + tid]   + gic_sh[Hn + tid];
      float gn = ge[2*Hn + tid] + gic_sh[2*Hn + tid];
      float r = fsigm(gr + qgh_sh[256 + tid]);
      float z = fsigm(gz + qgh_sh[512 + tid]);
      float n = ftanh(gn + r*qgh_sh[768 + tid]);
      float hn2 = (1.0f - z)*n + z*h_sh[tid];
      h_all[((size_t)t*Bn + b)*Hn + tid] = __float2bfloat16(hn2);
      if(t == Tn-1) hfin_out[b*Hn + tid] = hn2;
      h_sh[tid] = hn2;
      h_b16[tid] = (short)f2bu(hn2);
    }
    __syncthreads();
  }
}

// ---------------- deferred logits GEMM (bf16 MFMA) + log_softmax ----------------
__global__ __launch_bounds__(256) void k_logits(
    const short* __restrict__ h_all, const short* __restrict__ w_bf,
    const float* __restrict__ out_b,
    float* __restrict__ pmax, float* __restrict__ psum,
    const float* __restrict__ lse, float* __restrict__ dec_out,
    int pass)
{
  const int tid = threadIdx.x;
  const int wave = tid >> 6, lane = tid & 63;
  const int lr = lane & 15, lg = lane >> 4;
  const int n0 = blockIdx.x * 64;
  const int m0 = blockIdx.y * 64 + wave * 16;
  const short* aptr = h_all + (size_t)(m0 + lr)*Hn + lg*8;
  const short* bptr = w_bf  + (size_t)(n0 + lr)*Hn + lg*8;
  f32x4 acc0 = {0.f,0.f,0.f,0.f}, acc1 = {0.f,0.f,0.f,0.f};
  f32x4 acc2 = {0.f,0.f,0.f,0.f}, acc3 = {0.f,0.f,0.f,0.f};
  #pragma unroll
  for(int kk = 0; kk < 8; kk++){
    bf16x8 a  = *(const bf16x8*)(aptr + kk*32);
    bf16x8 b0 = *(const bf16x8*)(bptr + 0*16*Hn + kk*32);
    bf16x8 b1 = *(const bf16x8*)(bptr + 1*16*Hn + kk*32);
    bf16x8 b2 = *(const bf16x8*)(bptr + 2*16*Hn + kk*32);
    bf16x8 b3 = *(const bf16x8*)(bptr + 3*16*Hn + kk*32);
    acc0 = __builtin_amdgcn_mfma_f32_16x16x32_bf16(a, b0, acc0, 0, 0, 0);
    acc1 = __builtin_amdgcn_mfma_f32_16x16x32_bf16(a, b1, acc1, 0, 0, 0);
    acc2 = __builtin_amdgcn_mfma_f32_16x16x32_bf16(a, b2, acc2, 0, 0, 0);
    acc3 = __builtin_amdgcn_mfma_f32_16x16x32_bf16(a, b3, acc3, 0, 0, 0);
  }
  const float bias0 = out_b[n0 +  0 + lr];
  const float bias1 = out_b[n0 + 16 + lr];
  const float bias2 = out_b[n0 + 32 + lr];
  const float bias3 = out_b[n0 + 48 + lr];
  if(pass == 0){
    #pragma unroll
    for(int i = 0; i < 4; i++){
      float v0 = acc0[i] + bias0, v1 = acc1[i] + bias1;
      float v2 = acc2[i] + bias2, v3 = acc3[i] + bias3;
      float m = fmaxf(fmaxf(v0, v1), fmaxf(v2, v3));
      m = fmaxf(m, __shfl_xor(m, 1)); m = fmaxf(m, __shfl_xor(m, 2));
      m = fmaxf(m, __shfl_xor(m, 4)); m = fmaxf(m, __shfl_xor(m, 8));
      float s = __expf(v0 - m) + __expf(v1 - m) + __expf(v2 - m) + __expf(v3 - m);
      s += __shfl_xor(s, 1); s += __shfl_xor(s, 2);
      s += __shfl_xor(s, 4); s += __shfl_xor(s, 8);
      if(lr == 0){
        const int row = m0 + lg*4 + i;
        pmax[(size_t)blockIdx.x*3200 + row] = m;
        psum[(size_t)blockIdx.x*3200 + row] = s;
      }
    }
  } else {
    #pragma unroll
    for(int i = 0; i < 4; i++){
      const int row = m0 + lg*4 + i;
      const float l = lse[row];
      const int bb = row & 31, tt = row >> 5;
      float* dst = dec_out + (size_t)bb*((size_t)Tn*Vn) + (size_t)tt*Vn + n0;
      dst[ 0 + lr] = acc0[i] + bias0 - l;
      dst[16 + lr] = acc1[i] + bias1 - l;
      dst[32 + lr] = acc2[i] + bias2 - l;
      dst[48 + lr] = acc3[i] + bias3 - l;
    }
  }
}

__global__ __launch_bounds__(256) void k_lse(const float* __restrict__ pmax,
    const float* __restrict__ psum, float* __restrict__ lse)
{
  const int row = blockIdx.x*256 + threadIdx.x;
  if(row >= Tn*Bn) return;
  float m = -3.0e38f;
  for(int c = 0; c < Vn/64; c++) m = fmaxf(m, pmax[(size_t)c*3200 + row]);
  float s = 0.f;
  for(int c = 0; c < Vn/64; c++)
    s += psum[(size_t)c*3200 + row] * __expf(pmax[(size_t)c*3200 + row] - m);
  lse[row] = m + __logf(s);
}

// ---------------- launch ----------------
extern "C" void kernel_launch(void* const* d_in, const int* in_sizes, int n_in,
                              void* d_out, int out_size, void* d_ws, size_t ws_size,
                              hipStream_t stream)
{
  const float* enc_outputs = (const float*)d_in[0];
  const float* enc_hidden  = (const float*)d_in[1];
  const int*   target      = (const int*)d_in[2];
  const float* embedding   = (const float*)d_in[3];
  const float* Qw   = (const float*)d_in[4];
  const float* Qb   = (const float*)d_in[5];
  const float* Kw   = (const float*)d_in[6];
  const float* Kb   = (const float*)d_in[7];
  const float* Vw   = (const float*)d_in[8];
  const float* Vb   = (const float*)d_in[9];
  const float* W_ih = (const float*)d_in[10];
  const float* W_hh = (const float*)d_in[11];
  const float* b_ih = (const float*)d_in[12];
  const float* b_hh = (const float*)d_in[13];
  const float* out_w = (const float*)d_in[14];
  const float* out_b = (const float*)d_in[15];

  float* dec  = (float*)d_out;                       // (B,T,V) = 102,400,000 f32
  float* hfin = dec + (size_t)Bn*Tn*Vn;              // (1,B,H)
  float* atts = hfin + Bn*Hn;                        // (B,T,S)

  // Scratch inside the dec region (fully consumed before final pass overwrites):
  unsigned short* enc_kb16 = (unsigned short*)(dec);            // 524,288 f32 slots
  unsigned short* ekP      = (unsigned short*)(dec + 524288);   // 524,288 slots
  unsigned short* encW2b16 = (unsigned short*)(dec + 1048576);  // 1,572,864 slots
  float* gi_emb = dec + 2621440;                                // 2,457,600 f32
  float* W_ihT  = dec + 5079040;                                // 393,216 f32
  float* KwT    = dec + 5472256;                                // 65,536 f32
  float* pmax   = dec + 5537792;                                // 1,600,000 f32
  float* psum   = dec + 7137792;                                // 1,600,000 f32
  unsigned short* W1P = (unsigned short*)(dec + 8737792);       // 131,072 slots (ends 8,868,864)

  // ws: lse + h_all(bf16) + out_w(bf16)  (~18 MB)
  float* wsf = (float*)d_ws;
  float* lse = wsf;
  __hip_bfloat16* h_all = (__hip_bfloat16*)(wsf + 3200);
  __hip_bfloat16* w_bf  = h_all + (size_t)Tn*Bn*Hn;

  // prep
  k_tr    <<<dim3(8, 8),   dim3(256), 0, stream>>>(Kw, KwT, 256, 256);
  k_tr    <<<dim3(16, 24), dim3(256), 0, stream>>>(W_ih, W_ihT, 768, 512);
  k_packW1<<<dim3(128),    dim3(256), 0, stream>>>(Qw, W_hh, W1P);
  k_cvt   <<<dim3((Vn*Hn)/1024), dim3(256), 0, stream>>>(out_w, w_bf, Vn*Hn);
  k_enc2  <<<dim3(256), dim3(256), 0, stream>>>(enc_outputs, KwT, Kb, enc_kb16);
  k_packEk<<<dim3(512), dim3(256), 0, stream>>>(enc_kb16, ekP);
  k_encW2b<<<dim3(256), dim3(768), 0, stream>>>(enc_outputs, W_ihT, encW2b16);
  k_giemb2<<<dim3(200), dim3(768), 0, stream>>>(target, embedding, W_ihT, b_ih, gi_emb);

  // recurrence
  k_loop3 <<<dim3(Bn), dim3(512), 0, stream>>>(enc_hidden, ekP, encW2b16,
            W1P, Qb, b_hh, Vw, Vb, gi_emb, h_all, atts, hfin);

  // logits + log_softmax
  k_logits<<<dim3(Vn/64, (Tn*Bn)/64), dim3(256), 0, stream>>>(
            (const short*)h_all, (const short*)w_bf, out_b,
            pmax, psum, (const float*)nullptr, (float*)nullptr, 0);
  k_lse   <<<dim3(13), dim3(256), 0, stream>>>(pmax, psum, lse);
  k_logits<<<dim3(Vn/64, (Tn*Bn)/64), dim3(256), 0, stream>>>(
            (const short*)h_all, (const short*)w_bf, out_b,
            (float*)nullptr, (float*)nullptr, lse, dec, 1);
}

// Round 4
// 1466.580 us; speedup vs baseline: 3.5742x; 2.1247x over previous
//
#include <hip/hip_runtime.h>
#include <hip/hip_bf16.h>

// Decoder: B=32, S=128, H=256, V=32000, T=100
#define Bn 32
#define Sn 128
#define Hn 256
#define Vn 32000
#define Tn 100
#define GIn 768   // 3H
#define AGENT __HIP_MEMORY_SCOPE_AGENT

typedef __attribute__((ext_vector_type(8))) short bf16x8;
typedef __attribute__((ext_vector_type(4))) float f32x4;

__device__ __forceinline__ float frcp(float x){ return __builtin_amdgcn_rcpf(x); }
__device__ __forceinline__ float ftanh(float x){ return 1.0f - 2.0f*frcp(__expf(2.0f*x)+1.0f); }
__device__ __forceinline__ float fsigm(float x){ return frcp(1.0f + __expf(-x)); }
__device__ __forceinline__ float b2f(unsigned short u){
  unsigned int v = ((unsigned int)u) << 16; return __builtin_bit_cast(float, v);
}
__device__ __forceinline__ unsigned short f2bu(float f){ // RNE f32->bf16 bits
  unsigned int u = __builtin_bit_cast(unsigned int, f);
  u += 0x7FFFu + ((u >> 16) & 1u);
  return (unsigned short)(u >> 16);
}
__device__ __forceinline__ void st_ag(float* p, float v){
  __hip_atomic_store(p, v, __ATOMIC_RELAXED, AGENT);
}
__device__ __forceinline__ float ld_ag(float* p){
  return __hip_atomic_load(p, __ATOMIC_RELAXED, AGENT);
}

// ---------------- generic 32x32 tiled transpose: out(CxR) = in(RxC)^T ----------------
__global__ __launch_bounds__(256) void k_tr(const float* __restrict__ in,
    float* __restrict__ out, int R, int C)
{
  __shared__ float tile[32][33];
  const int bx = blockIdx.x*32, by = blockIdx.y*32;
  const int tx = threadIdx.x & 31, ty = threadIdx.x >> 5;
  #pragma unroll
  for(int r = ty; r < 32; r += 8)
    if(by + r < R && bx + tx < C) tile[r][tx] = in[(size_t)(by + r)*C + bx + tx];
  __syncthreads();
  #pragma unroll
  for(int r = ty; r < 32; r += 8)
    if(bx + r < C && by + tx < R) out[(size_t)(bx + r)*R + by + tx] = tile[tx][r];
}

// ---------------- W1R: [Qw;W_hh] bf16 as per-(half,wave) MFMA B-fragments ----------------
// Feature partition: half0 = {q rows 0-255, ghn rows 768-1023}; half1 = {ghr 256-511, ghz 512-767}
// dst elem: fragid*512 + lane*8 + j  with fragid = (hb*8+w)*32 + kk*4+tt
// src: feature f = base(hb,w) + (w&3)*64 + tt*16 + (lane&15), col = kk*32 + (lane>>4)*8
__global__ __launch_bounds__(256) void k_packW1R(const float* __restrict__ Qw,
    const float* __restrict__ Whh, unsigned short* __restrict__ W1R)
{
  const int tid = blockIdx.x*256 + threadIdx.x;   // 0..32767
  const int lane = tid & 63;
  const int fragid = tid >> 6;                    // 0..511
  const int frag = fragid & 31, w = (fragid >> 5) & 7, hb = fragid >> 8;
  const int kk = frag >> 2, tt = frag & 3;
  const int lr = lane & 15, lg = lane >> 4;
  const int base = (hb == 0) ? (w < 4 ? 0 : 768) : (w < 4 ? 256 : 512);
  const int f = base + (w & 3)*64 + tt*16 + lr;
  const int col = kk*32 + lg*8;
  const float* src = (f < 256 ? Qw + (size_t)f*Hn : Whh + (size_t)(f - 256)*Hn) + col;
  float4 v0 = *(const float4*)src, v1 = *(const float4*)(src + 4);
  unsigned short* d = W1R + ((size_t)fragid*64 + lane)*8;
  d[0]=f2bu(v0.x); d[1]=f2bu(v0.y); d[2]=f2bu(v0.z); d[3]=f2bu(v0.w);
  d[4]=f2bu(v1.x); d[5]=f2bu(v1.y); d[6]=f2bu(v1.z); d[7]=f2bu(v1.w);
}

// f32 -> bf16 (out_w)
__global__ __launch_bounds__(256) void k_cvt(const float* __restrict__ src,
    __hip_bfloat16* __restrict__ dst, int n)
{
  int i = (blockIdx.x*256 + threadIdx.x)*4;
  if(i < n){
    float4 v = *(const float4*)(src + i);
    dst[i+0] = __float2bfloat16(v.x);
    dst[i+1] = __float2bfloat16(v.y);
    dst[i+2] = __float2bfloat16(v.z);
    dst[i+3] = __float2bfloat16(v.w);
  }
}

// ---------------- enc_kb16[bs][j] = bf16( enc[bs,:]·KwT[:,j] + Kb[j] ) ----------------
__global__ __launch_bounds__(256) void k_enc2(const float* __restrict__ enc_outputs,
    const float* __restrict__ KwT, const float* __restrict__ Kb,
    unsigned short* __restrict__ enc_kb16)
{
  const int r0 = blockIdx.x*16, j = threadIdx.x;
  __shared__ __align__(16) float encl[Hn][20];
  #pragma unroll
  for(int r = 0; r < 16; r++) encl[j][r] = enc_outputs[(size_t)(r0 + r)*Hn + j];
  __syncthreads();
  float acc[16];
  #pragma unroll
  for(int r = 0; r < 16; r++) acc[r] = Kb[j];
  for(int d = 0; d < Hn; d++){
    const float wv = KwT[(size_t)d*Hn + j];
    const float4 e0 = *(const float4*)&encl[d][0];
    const float4 e1 = *(const float4*)&encl[d][4];
    const float4 e2 = *(const float4*)&encl[d][8];
    const float4 e3 = *(const float4*)&encl[d][12];
    acc[0]+=e0.x*wv; acc[1]+=e0.y*wv; acc[2]+=e0.z*wv; acc[3]+=e0.w*wv;
    acc[4]+=e1.x*wv; acc[5]+=e1.y*wv; acc[6]+=e1.z*wv; acc[7]+=e1.w*wv;
    acc[8]+=e2.x*wv; acc[9]+=e2.y*wv; acc[10]+=e2.z*wv; acc[11]+=e2.w*wv;
    acc[12]+=e3.x*wv; acc[13]+=e3.y*wv; acc[14]+=e3.z*wv; acc[15]+=e3.w*wv;
  }
  #pragma unroll
  for(int r = 0; r < 16; r++) enc_kb16[(size_t)(r0 + r)*Hn + j] = f2bu(acc[r]);
}

// ---------------- ekP: enc_k permuted to phase-2 consumption order ----------------
__global__ __launch_bounds__(256) void k_packEk(const unsigned short* __restrict__ enc_kb16,
    unsigned short* __restrict__ ekP)
{
  const int tid = blockIdx.x*256 + threadIdx.x;   // 0..131071
  const int b = tid >> 12;
  const int o = tid & 4095;
  const int g = o >> 6, l = o & 63;
  const int w = g >> 3, i = g & 7;
  const int s = w*16 + (l >> 2);
  const int e0 = i*32 + (l & 3)*8;
  const int4 v = *(const int4*)(enc_kb16 + ((size_t)(b*Sn + s))*Hn + e0);
  *(int4*)(ekP + (size_t)b*32768 + (size_t)o*8) = v;
}

// ---------------- encW2P[b][hb][c][s] = bf16( enc[b,s,:]·W_ihT[256+:, j] ), j = hb*384+c ----------------
__global__ __launch_bounds__(768) void k_encW2b(const float* __restrict__ enc_outputs,
    const float* __restrict__ W_ihT, unsigned short* __restrict__ encW2P)
{
  const int r0 = blockIdx.x*16, tid = threadIdx.x;
  __shared__ __align__(16) float encl[Hn][20];
  if(tid < Hn){
    #pragma unroll
    for(int r = 0; r < 16; r++) encl[tid][r] = enc_outputs[(size_t)(r0 + r)*Hn + tid];
  }
  __syncthreads();
  float acc[16];
  #pragma unroll
  for(int r = 0; r < 16; r++) acc[r] = 0.f;
  for(int d = 0; d < Hn; d++){
    const float wv = W_ihT[(size_t)(Hn + d)*GIn + tid];
    const float4 e0 = *(const float4*)&encl[d][0];
    const float4 e1 = *(const float4*)&encl[d][4];
    const float4 e2 = *(const float4*)&encl[d][8];
    const float4 e3 = *(const float4*)&encl[d][12];
    acc[0]+=e0.x*wv; acc[1]+=e0.y*wv; acc[2]+=e0.z*wv; acc[3]+=e0.w*wv;
    acc[4]+=e1.x*wv; acc[5]+=e1.y*wv; acc[6]+=e1.z*wv; acc[7]+=e1.w*wv;
    acc[8]+=e2.x*wv; acc[9]+=e2.y*wv; acc[10]+=e2.z*wv; acc[11]+=e2.w*wv;
    acc[12]+=e3.x*wv; acc[13]+=e3.y*wv; acc[14]+=e3.z*wv; acc[15]+=e3.w*wv;
  }
  const int hb = (tid >= 384) ? 1 : 0;
  const int c = tid - hb*384;
  #pragma unroll
  for(int r = 0; r < 16; r++){
    const int bs = r0 + r;
    const int bb = bs >> 7, ss = bs & 127;
    encW2P[(((size_t)bb*2 + hb)*384 + c)*128 + ss] = f2bu(acc[r]);
  }
}

// ---------------- gi_emb[t*32+b][j] = emb(tok)·W_ihT[:256, j] + b_ih[j]  (f32) ----------------
__global__ __launch_bounds__(768) void k_giemb2(const int* __restrict__ target,
    const float* __restrict__ embedding, const float* __restrict__ W_ihT,
    const float* __restrict__ b_ih, float* __restrict__ gi_emb)
{
  const int r0 = blockIdx.x*16, tid = threadIdx.x;
  __shared__ __align__(16) float embl[Hn][20];
  if(tid < Hn){
    #pragma unroll
    for(int r = 0; r < 16; r++){
      const int row = r0 + r;            // t*32+b
      const int t = row >> 5, b = row & 31;
      const int tok = (t == 0) ? 0 : target[b*Tn + (t-1)];
      embl[tid][r] = embedding[(size_t)tok*Hn + tid];
    }
  }
  __syncthreads();
  float acc[16];
  #pragma unroll
  for(int r = 0; r < 16; r++) acc[r] = b_ih[tid];
  for(int d = 0; d < Hn; d++){
    const float wv = W_ihT[(size_t)d*GIn + tid];
    const float4 e0 = *(const float4*)&embl[d][0];
    const float4 e1 = *(const float4*)&embl[d][4];
    const float4 e2 = *(const float4*)&embl[d][8];
    const float4 e3 = *(const float4*)&embl[d][12];
    acc[0]+=e0.x*wv; acc[1]+=e0.y*wv; acc[2]+=e0.z*wv; acc[3]+=e0.w*wv;
    acc[4]+=e1.x*wv; acc[5]+=e1.y*wv; acc[6]+=e1.z*wv; acc[7]+=e1.w*wv;
    acc[8]+=e2.x*wv; acc[9]+=e2.y*wv; acc[10]+=e2.z*wv; acc[11]+=e2.w*wv;
    acc[12]+=e3.x*wv; acc[13]+=e3.y*wv; acc[14]+=e3.z*wv; acc[15]+=e3.w*wv;
  }
  #pragma unroll
  for(int r = 0; r < 16; r++) gi_emb[(size_t)(r0 + r)*GIn + tid] = acc[r];
}

// ---------------- serial recurrence: 64 blocks (pair per batch row), all-resident ----------------
// Everything step-invariant lives in regs/LDS. Halves swap qgh (512 f32) and gi (384 f32)
// per step via agent-scope atomics + monotonic flags (memset per launch).
__global__ __launch_bounds__(512, 2) void k_loop4(
    const float* __restrict__ enc_hidden,
    const unsigned short* __restrict__ ekP,        // (B,32768) packed
    const unsigned short* __restrict__ encW2P,     // (B,2,384,128)
    const unsigned short* __restrict__ W1R,        // per-(half,wave) frags
    const float* __restrict__ Qb, const float* __restrict__ b_hh,
    const float* __restrict__ Vw, const float* __restrict__ Vb,
    const float* __restrict__ gi_emb,              // (T*B,3H) f32
    __hip_bfloat16* __restrict__ h_all,
    float* __restrict__ atts_out,
    float* __restrict__ hfin_out,
    float* qbuf,            // [2][32][2][512]
    float* gbuf,            // [2][32][2][384]
    unsigned int* qflag,    // [32][2]
    unsigned int* gflag)    // [32][2]
{
  // pair-mate co-XCD mapping: p = (i%8)*4 + i/16, half = (i/8)&1
  const int p = (blockIdx.x & 7)*4 + (blockIdx.x >> 4);
  const int half = (blockIdx.x >> 3) & 1;
  const int b = p;
  const int tid = threadIdx.x;
  const int lane = tid & 63, wv = tid >> 6;        // 8 waves
  const int lg = lane >> 4;

  __shared__ __align__(16) unsigned short ek_l[32768];    // 64 KB
  __shared__ __align__(16) unsigned short ew_l[256*136];  // 68 KB ([col][s] pad->272B stride)
  __shared__ __align__(16) float h_sh[Hn];
  __shared__ __align__(16) short h_b16[Hn];
  __shared__ __align__(16) float qgh_sh[1024];
  __shared__ __align__(16) float vw_sh[Hn];
  __shared__ __align__(16) float sc_sh[Sn];
  __shared__ __align__(16) float w_sh[Sn];
  __shared__ __align__(16) float gic_sh[GIn];

  // ---- one-time staging ----
  {　// ekP[b] -> LDS (identical for both halves)
    const unsigned short* src = ekP + (size_t)b*32768;
    #pragma unroll
    for(int c = 0; c < 8; c++){
      const int idx = (c*512 + tid)*8;
      *(int4*)(ek_l + idx) = *(const int4*)(src + idx);
    }
  }
  { // encW2P LDS part: cols 0..255 of this half's slice, [col][136] layout
    const unsigned short* src = encW2P + ((size_t)(b*2 + half)*384)*128;
    #pragma unroll
    for(int i = 0; i < 8; i++){
      const int id = i*512 + tid;         // 0..4095 chunks of 16B
      const int c = id >> 4, sc = id & 15;
      *(int4*)(ew_l + c*136 + sc*8) = *(const int4*)(src + (size_t)c*128 + sc*8);
    }
  }
  // encW2P register part: cols 256..383 -> 4 threads/col, 32 s each (16 VGPR)
  bf16x8 er0, er1, er2, er3;
  {
    const unsigned short* esrc = encW2P +
        ((size_t)((b*2 + half)*384 + 256 + (tid >> 2)))*128 + (tid & 3)*32;
    er0 = *(const bf16x8*)(esrc);
    er1 = *(const bf16x8*)(esrc + 8);
    er2 = *(const bf16x8*)(esrc + 16);
    er3 = *(const bf16x8*)(esrc + 24);
  }
  // W1 fragments: 32 per wave (128 VGPR)
  bf16x8 w1f[32];
  {
    const unsigned short* wsrc = W1R + (((size_t)(half*8 + wv)*32)*64 + lane)*8;
    #pragma unroll
    for(int f = 0; f < 32; f++) w1f[f] = *(const bf16x8*)(wsrc + (size_t)f*512);
  }
  const int fbase = (half == 0) ? (wv < 4 ? 0 : 768) : (wv < 4 ? 256 : 512);
  float bias_r[4];
  #pragma unroll
  for(int tt = 0; tt < 4; tt++){
    const int f = fbase + (wv & 3)*64 + tt*16 + (lane & 15);
    bias_r[tt] = (f < Hn) ? Qb[f] : b_hh[f - Hn];
  }
  if(tid < Hn){
    float hv = enc_hidden[b*Hn + tid];
    h_sh[tid] = hv; h_b16[tid] = (short)f2bu(hv);
    vw_sh[tid] = Vw[tid];
  }
  __syncthreads();
  const float vb0 = Vb[0];
  const int s2 = tid >> 2, g2 = tid & 3;

  for(int t = 0; t < Tn; t++){
    const int par = t & 1;
    // ---- phase 1: this half's 512 features of [q|ghr|ghz|ghn] = h @ W1.T (regs) ----
    {
      f32x4 acc[4];
      #pragma unroll
      for(int tt = 0; tt < 4; tt++) acc[tt] = (f32x4){0.f,0.f,0.f,0.f};
      #pragma unroll
      for(int kk = 0; kk < 8; kk++){
        bf16x8 a = *(const bf16x8*)(h_b16 + kk*32 + lg*8);
        #pragma unroll
        for(int tt = 0; tt < 4; tt++)
          acc[tt] = __builtin_amdgcn_mfma_f32_16x16x32_bf16(a, w1f[kk*4 + tt], acc[tt], 0, 0, 0);
      }
      if(lane < 16){
        #pragma unroll
        for(int tt = 0; tt < 4; tt++){
          const float v = acc[tt][0] + bias_r[tt];
          qgh_sh[fbase + (wv & 3)*64 + tt*16 + lane] = v;
          st_ag(&qbuf[((size_t)(par*32 + p)*2 + half)*512 + wv*64 + tt*16 + lane], v);
        }
      }
    }
    __syncthreads();                          // drains qbuf stores (vmcnt 0)
    if(tid == 0){
      __threadfence();
      __hip_atomic_store(&qflag[p*2 + half], (unsigned)(t + 1), __ATOMIC_RELEASE, AGENT);
      long cnt = 0;
      while(__hip_atomic_load(&qflag[p*2 + (half^1)], __ATOMIC_ACQUIRE, AGENT) < (unsigned)(t + 1)
            && ++cnt < 10000000L){}
    }
    __syncthreads();
    { // pull partner's 512 features
      const int pw = tid >> 6, rem = tid & 63;
      const int pbase = ((half^1) == 0) ? (pw < 4 ? 0 : 768) : (pw < 4 ? 256 : 512);
      const float v = ld_ag(&qbuf[((size_t)(par*32 + p)*2 + (half^1))*512 + tid]);
      qgh_sh[pbase + (pw & 3)*64 + rem] = v;
    }
    __syncthreads();

    // ---- phase 2: scores[s] = Vb + sum_h Vw[h]*tanh(q[h]+enc_k[b,s,h]) (LDS) ----
    {
      float pacc = 0.f;
      #pragma unroll
      for(int i = 0; i < 8; i++){
        bf16x8 e8 = *(const bf16x8*)(ek_l + ((wv*8 + i) << 9) + lane*8);
        const int kb = i*32 + g2*8;
        #pragma unroll
        for(int j = 0; j < 8; j++){
          float ev = b2f((unsigned short)e8[j]);
          pacc = fmaf(vw_sh[kb + j], ftanh(qgh_sh[kb + j] + ev), pacc);
        }
      }
      pacc += __shfl_xor(pacc, 1); pacc += __shfl_xor(pacc, 2);
      if(g2 == 0) sc_sh[s2] = pacc + vb0;
    }
    __syncthreads();

    // ---- softmax over S=128 (wave 0, both halves identically) ----
    if(tid < 64){
      float v0 = sc_sh[tid], v1 = sc_sh[tid + 64];
      float m = fmaxf(v0, v1);
      #pragma unroll
      for(int off = 1; off < 64; off <<= 1) m = fmaxf(m, __shfl_xor(m, off));
      float e0 = __expf(v0 - m), e1 = __expf(v1 - m);
      float sm = e0 + e1;
      #pragma unroll
      for(int off = 1; off < 64; off <<= 1) sm += __shfl_xor(sm, off);
      float inv = frcp(sm);
      float w0 = e0*inv, w1 = e1*inv;
      w_sh[tid] = w0; w_sh[tid + 64] = w1;
      if(half == 0){
        float* ao = atts_out + ((size_t)b*Tn + t)*Sn;
        ao[tid] = w0; ao[tid + 64] = w1;
      }
    }
    __syncthreads();

    // prefetch gi_emb for phase 4 (hides L2/L3 latency under phase 3)
    float ge0 = 0.f, ge1 = 0.f, ge2 = 0.f;
    if(tid < Hn){
      const float* ge = gi_emb + ((size_t)t*Bn + b)*GIn;
      ge0 = ge[tid]; ge1 = ge[Hn + tid]; ge2 = ge[2*Hn + tid];
    }

    // ---- phase 3: gi_ctx slice (384 cols) from LDS[256 cols] + regs[128 cols] ----
    {
      // LDS part: col c3 = tid>>1, s-half s3 = (tid&1)*64
      const int c3 = tid >> 1, s3 = (tid & 1)*64;
      float a3 = 0.f;
      #pragma unroll
      for(int i = 0; i < 8; i++){
        bf16x8 e = *(const bf16x8*)(ew_l + c3*136 + s3 + i*8);
        const float4 wa = *(const float4*)&w_sh[s3 + i*8];
        const float4 wb = *(const float4*)&w_sh[s3 + i*8 + 4];
        a3 = fmaf(wa.x, b2f((unsigned short)e[0]), a3);
        a3 = fmaf(wa.y, b2f((unsigned short)e[1]), a3);
        a3 = fmaf(wa.z, b2f((unsigned short)e[2]), a3);
        a3 = fmaf(wa.w, b2f((unsigned short)e[3]), a3);
        a3 = fmaf(wb.x, b2f((unsigned short)e[4]), a3);
        a3 = fmaf(wb.y, b2f((unsigned short)e[5]), a3);
        a3 = fmaf(wb.z, b2f((unsigned short)e[6]), a3);
        a3 = fmaf(wb.w, b2f((unsigned short)e[7]), a3);
      }
      a3 += __shfl_xor(a3, 1);
      if((tid & 1) == 0){
        gic_sh[half*384 + c3] = a3;
        st_ag(&gbuf[((size_t)(par*32 + p)*2 + half)*384 + c3], a3);
      }
      // reg part: col cr = tid>>2, s-quarter sq = tid&3
      const float* wq = &w_sh[(tid & 3)*32];
      float r2 = 0.f;
      #pragma unroll
      for(int j = 0; j < 8; j++) r2 = fmaf(wq[j],      b2f((unsigned short)er0[j]), r2);
      #pragma unroll
      for(int j = 0; j < 8; j++) r2 = fmaf(wq[8 + j],  b2f((unsigned short)er1[j]), r2);
      #pragma unroll
      for(int j = 0; j < 8; j++) r2 = fmaf(wq[16 + j], b2f((unsigned short)er2[j]), r2);
      #pragma unroll
      for(int j = 0; j < 8; j++) r2 = fmaf(wq[24 + j], b2f((unsigned short)er3[j]), r2);
      r2 += __shfl_xor(r2, 1); r2 += __shfl_xor(r2, 2);
      if((tid & 3) == 0){
        const int c = 256 + (tid >> 2);
        gic_sh[half*384 + c] = r2;
        st_ag(&gbuf[((size_t)(par*32 + p)*2 + half)*384 + c], r2);
      }
    }
    __syncthreads();                          // drains gbuf stores
    if(tid == 0){
      __threadfence();
      __hip_atomic_store(&gflag[p*2 + half], (unsigned)(t + 1), __ATOMIC_RELEASE, AGENT);
      long cnt = 0;
      while(__hip_atomic_load(&gflag[p*2 + (half^1)], __ATOMIC_ACQUIRE, AGENT) < (unsigned)(t + 1)
            && ++cnt < 10000000L){}
    }
    __syncthreads();
    if(tid < 384)
      gic_sh[(half^1)*384 + tid] = ld_ag(&gbuf[((size_t)(par*32 + p)*2 + (half^1))*384 + tid]);
    __syncthreads();

    // ---- phase 4: GRU cell (f32, both halves identically) ----
    if(tid < Hn){
      float gr = ge0 + gic_sh[tid];
      float gz = ge1 + gic_sh[Hn + tid];
      float gn = ge2 + gic_sh[2*Hn + tid];
      float r = fsigm(gr + qgh_sh[256 + tid]);
      float z = fsigm(gz + qgh_sh[512 + tid]);
      float n = ftanh(gn + r*qgh_sh[768 + tid]);
      float hn2 = (1.0f - z)*n + z*h_sh[tid];
      if(half == 0){
        h_all[((size_t)t*Bn + b)*Hn + tid] = __float2bfloat16(hn2);
        if(t == Tn-1) hfin_out[b*Hn + tid] = hn2;
      }
      h_sh[tid] = hn2;
      h_b16[tid] = (short)f2bu(hn2);
    }
    __syncthreads();
  }
}

// ---------------- deferred logits GEMM: 256x256 tiles, 8 waves ----------------
__global__ __launch_bounds__(512, 2) void k_logits2(
    const short* __restrict__ h_all, const short* __restrict__ w_bf,
    const float* __restrict__ out_b,
    float* __restrict__ pmax, float* __restrict__ psum,
    const float* __restrict__ lse, float* __restrict__ dec_out,
    int pass)
{
  const int tid = threadIdx.x;
  const int wave = tid >> 6, lane = tid & 63;
  const int lr = lane & 15, lg = lane >> 4;
  const int wm = wave >> 2, wn = wave & 3;
  const int n0 = blockIdx.x*256 + wn*64;
  const int m0 = blockIdx.y*256 + wm*128;
  f32x4 acc[8][4];
  #pragma unroll
  for(int mt = 0; mt < 8; mt++)
    #pragma unroll
    for(int nt = 0; nt < 4; nt++) acc[mt][nt] = (f32x4){0.f,0.f,0.f,0.f};
  #pragma unroll
  for(int kk = 0; kk < 8; kk++){
    bf16x8 am[8], bn[4];
    #pragma unroll
    for(int mt = 0; mt < 8; mt++){
      int row = m0 + mt*16 + lr; row = row < 3200 ? row : 3199;
      am[mt] = *(const bf16x8*)(h_all + (size_t)row*Hn + kk*32 + lg*8);
    }
    #pragma unroll
    for(int nt = 0; nt < 4; nt++)
      bn[nt] = *(const bf16x8*)(w_bf + (size_t)(n0 + nt*16 + lr)*Hn + kk*32 + lg*8);
    #pragma unroll
    for(int mt = 0; mt < 8; mt++)
      #pragma unroll
      for(int nt = 0; nt < 4; nt++)
        acc[mt][nt] = __builtin_amdgcn_mfma_f32_16x16x32_bf16(am[mt], bn[nt], acc[mt][nt], 0, 0, 0);
  }
  float bias[4];
  #pragma unroll
  for(int nt = 0; nt < 4; nt++) bias[nt] = out_b[n0 + nt*16 + lr];

  if(pass == 0){
    __shared__ float pm_l[256][4];
    __shared__ float ps_l[256][4];
    #pragma unroll
    for(int mt = 0; mt < 8; mt++){
      #pragma unroll
      for(int i = 0; i < 4; i++){
        float v0 = acc[mt][0][i] + bias[0], v1 = acc[mt][1][i] + bias[1];
        float v2 = acc[mt][2][i] + bias[2], v3 = acc[mt][3][i] + bias[3];
        float m = fmaxf(fmaxf(v0, v1), fmaxf(v2, v3));
        m = fmaxf(m, __shfl_xor(m, 1)); m = fmaxf(m, __shfl_xor(m, 2));
        m = fmaxf(m, __shfl_xor(m, 4)); m = fmaxf(m, __shfl_xor(m, 8));
        float s = __expf(v0 - m) + __expf(v1 - m) + __expf(v2 - m) + __expf(v3 - m);
        s += __shfl_xor(s, 1); s += __shfl_xor(s, 2);
        s += __shfl_xor(s, 4); s += __shfl_xor(s, 8);
        if(lr == 0){
          const int rl = wm*128 + mt*16 + lg*4 + i;
          pm_l[rl][wn] = m; ps_l[rl][wn] = s;
        }
      }
    }
    __syncthreads();
    if(tid < 256){
      const int rg = blockIdx.y*256 + tid;
      if(rg < 3200){
        float m = fmaxf(fmaxf(pm_l[tid][0], pm_l[tid][1]), fmaxf(pm_l[tid][2], pm_l[tid][3]));
        float s = ps_l[tid][0]*__expf(pm_l[tid][0] - m) + ps_l[tid][1]*__expf(pm_l[tid][1] - m)
                + ps_l[tid][2]*__expf(pm_l[tid][2] - m) + ps_l[tid][3]*__expf(pm_l[tid][3] - m);
        pmax[(size_t)blockIdx.x*3200 + rg] = m;
        psum[(size_t)blockIdx.x*3200 + rg] = s;
      }
    }
  } else {
    #pragma unroll
    for(int mt = 0; mt < 8; mt++){
      #pragma unroll
      for(int i = 0; i < 4; i++){
        const int rg = blockIdx.y*256 + wm*128 + mt*16 + lg*4 + i;
        if(rg < 3200){
          const float l = lse[rg];
          const int bb = rg & 31, tt2 = rg >> 5;
          float* dst = dec_out + (size_t)bb*((size_t)Tn*Vn) + (size_t)tt2*Vn + n0;
          dst[ 0 + lr] = acc[mt][0][i] + bias[0] - l;
          dst[16 + lr] = acc[mt][1][i] + bias[1] - l;
          dst[32 + lr] = acc[mt][2][i] + bias[2] - l;
          dst[48 + lr] = acc[mt][3][i] + bias[3] - l;
        }
      }
    }
  }
}

__global__ __launch_bounds__(256) void k_lse(const float* __restrict__ pmax,
    const float* __restrict__ psum, float* __restrict__ lse)
{
  const int row = blockIdx.x*256 + threadIdx.x;
  if(row >= Tn*Bn) return;
  float m = -3.0e38f;
  for(int c = 0; c < 125; c++) m = fmaxf(m, pmax[(size_t)c*3200 + row]);
  float s = 0.f;
  for(int c = 0; c < 125; c++)
    s += psum[(size_t)c*3200 + row] * __expf(pmax[(size_t)c*3200 + row] - m);
  lse[row] = m + __logf(s);
}

// ---------------- launch ----------------
extern "C" void kernel_launch(void* const* d_in, const int* in_sizes, int n_in,
                              void* d_out, int out_size, void* d_ws, size_t ws_size,
                              hipStream_t stream)
{
  const float* enc_outputs = (const float*)d_in[0];
  const float* enc_hidden  = (const float*)d_in[1];
  const int*   target      = (const int*)d_in[2];
  const float* embedding   = (const float*)d_in[3];
  const float* Qw   = (const float*)d_in[4];
  const float* Qb   = (const float*)d_in[5];
  const float* Kw   = (const float*)d_in[6];
  const float* Kb   = (const float*)d_in[7];
  const float* Vw   = (const float*)d_in[8];
  const float* Vb   = (const float*)d_in[9];
  const float* W_ih = (const float*)d_in[10];
  const float* W_hh = (const float*)d_in[11];
  const float* b_ih = (const float*)d_in[12];
  const float* b_hh = (const float*)d_in[13];
  const float* out_w = (const float*)d_in[14];
  const float* out_b = (const float*)d_in[15];

  float* dec  = (float*)d_out;                       // (B,T,V) = 102,400,000 f32
  float* hfin = dec + (size_t)Bn*Tn*Vn;              // (1,B,H)
  float* atts = hfin + Bn*Hn;                        // (B,T,S)

  // Scratch inside dec region (fully consumed before final pass overwrites):
  unsigned short* enc_kb16 = (unsigned short*)(dec);            // 524,288 f32 slots
  unsigned short* ekP      = (unsigned short*)(dec + 524288);   // 524,288
  unsigned short* encW2P   = (unsigned short*)(dec + 1048576);  // 1,572,864
  float* gi_emb = dec + 2621440;                                // 2,457,600
  float* W_ihT  = dec + 5079040;                                // 393,216
  float* KwT    = dec + 5472256;                                // 65,536
  float* pmax   = dec + 5537792;                                // 400,000
  float* psum   = dec + 5937792;                                // 400,000
  unsigned short* W1R = (unsigned short*)(dec + 6337792);       // 131,072 slots
  float* qbuf   = dec + 6468864;                                // 65,536
  float* gbuf   = dec + 6534400;                                // 49,152
  unsigned int* qflag = (unsigned int*)(dec + 6583552);         // 64
  unsigned int* gflag = qflag + 64;                             // 64 (ends 6,583,680)

  // ws: lse + h_all(bf16) + out_w(bf16)
  float* wsf = (float*)d_ws;
  float* lse = wsf;
  __hip_bfloat16* h_all = (__hip_bfloat16*)(wsf + 3200);
  __hip_bfloat16* w_bf  = h_all + (size_t)Tn*Bn*Hn;

  // prep
  k_tr     <<<dim3(8, 8),   dim3(256), 0, stream>>>(Kw, KwT, 256, 256);
  k_tr     <<<dim3(16, 24), dim3(256), 0, stream>>>(W_ih, W_ihT, 768, 512);
  k_packW1R<<<dim3(128),    dim3(256), 0, stream>>>(Qw, W_hh, W1R);
  k_cvt    <<<dim3((Vn*Hn)/1024), dim3(256), 0, stream>>>(out_w, w_bf, Vn*Hn);
  k_enc2   <<<dim3(256), dim3(256), 0, stream>>>(enc_outputs, KwT, Kb, enc_kb16);
  k_packEk <<<dim3(512), dim3(256), 0, stream>>>(enc_kb16, ekP);
  k_encW2b <<<dim3(256), dim3(768), 0, stream>>>(enc_outputs, W_ihT, encW2P);
  k_giemb2 <<<dim3(200), dim3(768), 0, stream>>>(target, embedding, W_ihT, b_ih, gi_emb);

  // reset pair flags (graph-captured, stream-ordered before k_loop4)
  hipMemsetAsync((void*)qflag, 0, 128*sizeof(unsigned int), stream);

  // recurrence: 64 co-resident blocks (2 per batch row)
  k_loop4 <<<dim3(64), dim3(512), 0, stream>>>(enc_hidden, ekP, encW2P, W1R,
            Qb, b_hh, Vw, Vb, gi_emb, h_all, atts, hfin,
            qbuf, gbuf, qflag, gflag);

  // logits + log_softmax
  k_logits2<<<dim3(125, 13), dim3(512), 0, stream>>>(
            (const short*)h_all, (const short*)w_bf, out_b,
            pmax, psum, (const float*)nullptr, (float*)nullptr, 0);
  k_lse    <<<dim3(13), dim3(256), 0, stream>>>(pmax, psum, lse);
  k_logits2<<<dim3(125, 13), dim3(512), 0, stream>>>(
            (const short*)h_all, (const short*)w_bf, out_b,
            (float*)nullptr, (float*)nullptr, lse, dec, 1);
}

// Round 5
// 1372.939 us; speedup vs baseline: 3.8179x; 1.0682x over previous
//
#include <hip/hip_runtime.h>
#include <hip/hip_bf16.h>

// Decoder: B=32, S=128, H=256, V=32000, T=100
#define Bn 32
#define Sn 128
#define Hn 256
#define Vn 32000
#define Tn 100
#define GIn 768   // 3H
#define AGENT __HIP_MEMORY_SCOPE_AGENT

typedef __attribute__((ext_vector_type(8))) short bf16x8;
typedef __attribute__((ext_vector_type(4))) float f32x4;

__device__ __forceinline__ float frcp(float x){ return __builtin_amdgcn_rcpf(x); }
__device__ __forceinline__ float ftanh(float x){ return 1.0f - 2.0f*frcp(__expf(2.0f*x)+1.0f); }
__device__ __forceinline__ float fsigm(float x){ return frcp(1.0f + __expf(-x)); }
__device__ __forceinline__ float b2f(unsigned short u){
  unsigned int v = ((unsigned int)u) << 16; return __builtin_bit_cast(float, v);
}
__device__ __forceinline__ unsigned short f2bu(float f){ // RNE f32->bf16 bits
  unsigned int u = __builtin_bit_cast(unsigned int, f);
  u += 0x7FFFu + ((u >> 16) & 1u);
  return (unsigned short)(u >> 16);
}
__device__ __forceinline__ void st_ag_u(unsigned int* p, unsigned int v){
  __hip_atomic_store(p, v, __ATOMIC_RELAXED, AGENT);
}
__device__ __forceinline__ unsigned int ld_ag_u(unsigned int* p){
  return __hip_atomic_load(p, __ATOMIC_RELAXED, AGENT);
}

// ---------------- generic 32x32 tiled transpose: out(CxR) = in(RxC)^T ----------------
__global__ __launch_bounds__(256) void k_tr(const float* __restrict__ in,
    float* __restrict__ out, int R, int C)
{
  __shared__ float tile[32][33];
  const int bx = blockIdx.x*32, by = blockIdx.y*32;
  const int tx = threadIdx.x & 31, ty = threadIdx.x >> 5;
  #pragma unroll
  for(int r = ty; r < 32; r += 8)
    if(by + r < R && bx + tx < C) tile[r][tx] = in[(size_t)(by + r)*C + bx + tx];
  __syncthreads();
  #pragma unroll
  for(int r = ty; r < 32; r += 8)
    if(bx + r < C && by + tx < R) out[(size_t)(bx + r)*R + by + tx] = tile[tx][r];
}

// ---------------- W1R: per-(half,wave) MFMA B-fragments --------------------------
// Per (hb, w): 40 frags, fragid_local = kk*5 + tt.
//   tt 0..1 : Qw rows  f = w*32 + tt*16 + lr          (redundant across halves)
//   tt 2..4 : W_hh rows for gate g, slice jj: lf = w*48 + (tt-2)*16 + lr,
//             g = lf>>7, jj = lf&127, row = g*256 + hb*128 + jj
// dst: W1R[(((hb*8+w)*40 + fid)*64 + lane)*8 + j], col = kk*32 + lg*8 + j
__global__ __launch_bounds__(256) void k_packW1R(const float* __restrict__ Qw,
    const float* __restrict__ Whh, unsigned short* __restrict__ W1R)
{
  const int tid = blockIdx.x*256 + threadIdx.x;   // 0..40959
  const int lane = tid & 63;
  const int fragid = tid >> 6;                    // 0..639
  const int tt = fragid % 5;
  const int kk = (fragid/5) % 8;
  const int w  = (fragid/40) % 8;
  const int hb = fragid/320;
  const int lr = lane & 15, lg = lane >> 4;
  const float* src;
  if(tt < 2){
    const int f = w*32 + tt*16 + lr;
    src = Qw + (size_t)f*Hn;
  } else {
    const int lf = w*48 + (tt-2)*16 + lr;
    const int g = lf >> 7, jj = lf & 127;
    src = Whh + (size_t)(g*256 + hb*128 + jj)*Hn;
  }
  const int col = kk*32 + lg*8;
  float4 v0 = *(const float4*)(src + col), v1 = *(const float4*)(src + col + 4);
  unsigned short* d = W1R + ((size_t)fragid*64 + lane)*8;
  d[0]=f2bu(v0.x); d[1]=f2bu(v0.y); d[2]=f2bu(v0.z); d[3]=f2bu(v0.w);
  d[4]=f2bu(v1.x); d[5]=f2bu(v1.y); d[6]=f2bu(v1.z); d[7]=f2bu(v1.w);
}

// f32 -> bf16 (out_w)
__global__ __launch_bounds__(256) void k_cvt(const float* __restrict__ src,
    __hip_bfloat16* __restrict__ dst, int n)
{
  int i = (blockIdx.x*256 + threadIdx.x)*4;
  if(i < n){
    float4 v = *(const float4*)(src + i);
    dst[i+0] = __float2bfloat16(v.x);
    dst[i+1] = __float2bfloat16(v.y);
    dst[i+2] = __float2bfloat16(v.z);
    dst[i+3] = __float2bfloat16(v.w);
  }
}

// ---------------- enc_kb16[bs][j] = bf16( enc[bs,:]·KwT[:,j] + Kb[j] ) ----------------
__global__ __launch_bounds__(256) void k_enc2(const float* __restrict__ enc_outputs,
    const float* __restrict__ KwT, const float* __restrict__ Kb,
    unsigned short* __restrict__ enc_kb16)
{
  const int r0 = blockIdx.x*16, j = threadIdx.x;
  __shared__ __align__(16) float encl[Hn][20];
  #pragma unroll
  for(int r = 0; r < 16; r++) encl[j][r] = enc_outputs[(size_t)(r0 + r)*Hn + j];
  __syncthreads();
  float acc[16];
  #pragma unroll
  for(int r = 0; r < 16; r++) acc[r] = Kb[j];
  for(int d = 0; d < Hn; d++){
    const float wv = KwT[(size_t)d*Hn + j];
    const float4 e0 = *(const float4*)&encl[d][0];
    const float4 e1 = *(const float4*)&encl[d][4];
    const float4 e2 = *(const float4*)&encl[d][8];
    const float4 e3 = *(const float4*)&encl[d][12];
    acc[0]+=e0.x*wv; acc[1]+=e0.y*wv; acc[2]+=e0.z*wv; acc[3]+=e0.w*wv;
    acc[4]+=e1.x*wv; acc[5]+=e1.y*wv; acc[6]+=e1.z*wv; acc[7]+=e1.w*wv;
    acc[8]+=e2.x*wv; acc[9]+=e2.y*wv; acc[10]+=e2.z*wv; acc[11]+=e2.w*wv;
    acc[12]+=e3.x*wv; acc[13]+=e3.y*wv; acc[14]+=e3.z*wv; acc[15]+=e3.w*wv;
  }
  #pragma unroll
  for(int r = 0; r < 16; r++) enc_kb16[(size_t)(r0 + r)*Hn + j] = f2bu(acc[r]);
}

// ---------------- ekP: enc_k permuted to phase-2 consumption order ----------------
__global__ __launch_bounds__(256) void k_packEk(const unsigned short* __restrict__ enc_kb16,
    unsigned short* __restrict__ ekP)
{
  const int tid = blockIdx.x*256 + threadIdx.x;   // 0..131071
  const int b = tid >> 12;
  const int o = tid & 4095;
  const int g = o >> 6, l = o & 63;
  const int w = g >> 3, i = g & 7;
  const int s = w*16 + (l >> 2);
  const int e0 = i*32 + (l & 3)*8;
  const int4 v = *(const int4*)(enc_kb16 + ((size_t)(b*Sn + s))*Hn + e0);
  *(int4*)(ekP + (size_t)b*32768 + (size_t)o*8) = v;
}

// ---------------- encW2P[b][hb][c][s], c = g*128 + (jj&127), hb = jj>>7 ----------------
// col j of enc@W_ih2.T: g = j>>8 (gate), jj = j&255 (h-dim)
__global__ __launch_bounds__(768) void k_encW2b(const float* __restrict__ enc_outputs,
    const float* __restrict__ W_ihT, unsigned short* __restrict__ encW2P)
{
  const int r0 = blockIdx.x*16, tid = threadIdx.x;
  __shared__ __align__(16) float encl[Hn][20];
  if(tid < Hn){
    #pragma unroll
    for(int r = 0; r < 16; r++) encl[tid][r] = enc_outputs[(size_t)(r0 + r)*Hn + tid];
  }
  __syncthreads();
  float acc[16];
  #pragma unroll
  for(int r = 0; r < 16; r++) acc[r] = 0.f;
  for(int d = 0; d < Hn; d++){
    const float wv = W_ihT[(size_t)(Hn + d)*GIn + tid];
    const float4 e0 = *(const float4*)&encl[d][0];
    const float4 e1 = *(const float4*)&encl[d][4];
    const float4 e2 = *(const float4*)&encl[d][8];
    const float4 e3 = *(const float4*)&encl[d][12];
    acc[0]+=e0.x*wv; acc[1]+=e0.y*wv; acc[2]+=e0.z*wv; acc[3]+=e0.w*wv;
    acc[4]+=e1.x*wv; acc[5]+=e1.y*wv; acc[6]+=e1.z*wv; acc[7]+=e1.w*wv;
    acc[8]+=e2.x*wv; acc[9]+=e2.y*wv; acc[10]+=e2.z*wv; acc[11]+=e2.w*wv;
    acc[12]+=e3.x*wv; acc[13]+=e3.y*wv; acc[14]+=e3.z*wv; acc[15]+=e3.w*wv;
  }
  const int g = tid >> 8, jj = tid & 255;
  const int hb = jj >> 7, c = g*128 + (jj & 127);
  #pragma unroll
  for(int r = 0; r < 16; r++){
    const int bs = r0 + r;
    const int bb = bs >> 7, ss = bs & 127;
    encW2P[(((size_t)bb*2 + hb)*384 + c)*128 + ss] = f2bu(acc[r]);
  }
}

// ---------------- gi_emb[t*32+b][j] = emb(tok)·W_ihT[:256, j] + b_ih[j]  (f32) ----------------
__global__ __launch_bounds__(768) void k_giemb2(const int* __restrict__ target,
    const float* __restrict__ embedding, const float* __restrict__ W_ihT,
    const float* __restrict__ b_ih, float* __restrict__ gi_emb)
{
  const int r0 = blockIdx.x*16, tid = threadIdx.x;
  __shared__ __align__(16) float embl[Hn][20];
  if(tid < Hn){
    #pragma unroll
    for(int r = 0; r < 16; r++){
      const int row = r0 + r;            // t*32+b
      const int t = row >> 5, b = row & 31;
      const int tok = (t == 0) ? 0 : target[b*Tn + (t-1)];
      embl[tid][r] = embedding[(size_t)tok*Hn + tid];
    }
  }
  __syncthreads();
  float acc[16];
  #pragma unroll
  for(int r = 0; r < 16; r++) acc[r] = b_ih[tid];
  for(int d = 0; d < Hn; d++){
    const float wv = W_ihT[(size_t)d*GIn + tid];
    const float4 e0 = *(const float4*)&embl[d][0];
    const float4 e1 = *(const float4*)&embl[d][4];
    const float4 e2 = *(const float4*)&embl[d][8];
    const float4 e3 = *(const float4*)&embl[d][12];
    acc[0]+=e0.x*wv; acc[1]+=e0.y*wv; acc[2]+=e0.z*wv; acc[3]+=e0.w*wv;
    acc[4]+=e1.x*wv; acc[5]+=e1.y*wv; acc[6]+=e1.z*wv; acc[7]+=e1.w*wv;
    acc[8]+=e2.x*wv; acc[9]+=e2.y*wv; acc[10]+=e2.z*wv; acc[11]+=e2.w*wv;
    acc[12]+=e3.x*wv; acc[13]+=e3.y*wv; acc[14]+=e3.z*wv; acc[15]+=e3.w*wv;
  }
  #pragma unroll
  for(int r = 0; r < 16; r++) gi_emb[(size_t)(r0 + r)*GIn + tid] = acc[r];
}

// ---------------- serial recurrence: 64 blocks (2 per row, j-split), ONE 256B swap/step ----
__global__ __launch_bounds__(512, 2) void k_loop5(
    const float* __restrict__ enc_hidden,
    const unsigned short* __restrict__ ekP,        // (B,32768) packed
    const unsigned short* __restrict__ encW2P,     // (B,2,384,128)
    const unsigned short* __restrict__ W1R,        // (2,8,40,64,8)
    const float* __restrict__ Qb, const float* __restrict__ b_hh,
    const float* __restrict__ Vw, const float* __restrict__ Vb,
    const float* __restrict__ gi_emb,              // (T*B,3H) f32
    __hip_bfloat16* __restrict__ h_all,
    float* __restrict__ atts_out,
    float* __restrict__ hfin_out,
    unsigned int* hbuf,            // [2][32][2][64] uint (128 bf16 each)
    unsigned int* hflag)           // [32][2]
{
  const int p = blockIdx.x >> 1, hb = blockIdx.x & 1, b = p;
  const int tid = threadIdx.x;
  const int lane = tid & 63, wv = tid >> 6;        // 8 waves
  const int lr = lane & 15, lg = lane >> 4;

  __shared__ __align__(16) unsigned short ek_l[32768];   // 64 KB
  __shared__ __align__(16) unsigned short ew_l[32768];   // 64 KB [c][128] swizzled
  __shared__ __align__(16) float h_sh[128];              // own slice, f32
  __shared__ __align__(16) short h_b16[Hn];              // full h, bf16
  __shared__ __align__(16) float qgh_sh[1024];
  __shared__ __align__(16) float vw_sh[Hn];
  __shared__ __align__(16) float sc_sh[Sn];
  __shared__ __align__(16) float w_sh[Sn];
  __shared__ __align__(16) float gic_l[384];             // own local gi_ctx

  // ---- one-time staging ----
  { // ekP[b] -> LDS (identical both halves)
    const unsigned short* src = ekP + (size_t)b*32768;
    #pragma unroll
    for(int c = 0; c < 8; c++){
      const int idx = (c*512 + tid)*8;
      *(int4*)(ek_l + idx) = *(const int4*)(src + idx);
    }
  }
  { // encW2P cols 0..255 of own slice -> LDS, XOR group-swizzle sg' = sg ^ (c&15)
    const unsigned short* src = encW2P + ((size_t)(b*2 + hb)*384)*128;
    #pragma unroll
    for(int i = 0; i < 8; i++){
      const int id = i*512 + tid;          // 0..4095 (c = id>>4, sg = id&15)
      const int c = id >> 4, sg = id & 15;
      *(int4*)(ew_l + c*128 + ((sg ^ (c & 15)) << 3)) =
          *(const int4*)(src + (size_t)c*128 + sg*8);
    }
  }
  // encW2P cols 256..383 (n-gate) -> regs: 4 threads/col, 32 s each
  bf16x8 er0, er1, er2, er3;
  {
    const unsigned short* esrc = encW2P +
        ((size_t)((b*2 + hb)*384 + 256 + (tid >> 2)))*128 + (tid & 3)*32;
    er0 = *(const bf16x8*)(esrc);
    er1 = *(const bf16x8*)(esrc + 8);
    er2 = *(const bf16x8*)(esrc + 16);
    er3 = *(const bf16x8*)(esrc + 24);
  }
  // W1 fragments: 40 per wave (160 VGPR): Qw full (tt 0-1) + W_hh own slice (tt 2-4)
  bf16x8 w1f[40];
  {
    const unsigned short* wsrc = W1R + (((size_t)(hb*8 + wv)*40)*64 + lane)*8;
    #pragma unroll
    for(int f = 0; f < 40; f++) w1f[f] = *(const bf16x8*)(wsrc + (size_t)f*512);
  }
  float bias_r[5]; int idx_r[5];
  #pragma unroll
  for(int tt = 0; tt < 2; tt++){
    const int f = wv*32 + tt*16 + lr;
    bias_r[tt] = Qb[f]; idx_r[tt] = f;
  }
  #pragma unroll
  for(int tt = 2; tt < 5; tt++){
    const int lf = wv*48 + (tt-2)*16 + lr;
    const int g = lf >> 7, jj = lf & 127;
    bias_r[tt] = b_hh[g*256 + hb*128 + jj];
    idx_r[tt]  = 256 + g*256 + hb*128 + jj;
  }
  if(tid < Hn){
    float hv = enc_hidden[b*Hn + tid];
    h_b16[tid] = (short)f2bu(hv);
    vw_sh[tid] = Vw[tid];
  }
  if(tid < 128) h_sh[tid] = enc_hidden[b*Hn + hb*128 + tid];
  __syncthreads();
  const float vb0 = Vb[0];
  const int s2 = tid >> 2, g2 = tid & 3;

  for(int t = 0; t < Tn; t++){
    const int par = t & 1;
    // ---- phase 1: q (full, redundant) + gh own slice = h @ W1.T (reg-resident) ----
    {
      f32x4 acc[5];
      #pragma unroll
      for(int tt = 0; tt < 5; tt++) acc[tt] = (f32x4){0.f,0.f,0.f,0.f};
      #pragma unroll
      for(int kk = 0; kk < 8; kk++){
        bf16x8 a = *(const bf16x8*)(h_b16 + kk*32 + lg*8);
        #pragma unroll
        for(int tt = 0; tt < 5; tt++)
          acc[tt] = __builtin_amdgcn_mfma_f32_16x16x32_bf16(a, w1f[kk*5 + tt], acc[tt], 0, 0, 0);
      }
      if(lane < 16){
        #pragma unroll
        for(int tt = 0; tt < 5; tt++)
          qgh_sh[idx_r[tt]] = acc[tt][0] + bias_r[tt];
      }
    }
    __syncthreads();

    // ---- phase 2: scores[s] = Vb + sum_h Vw[h]*tanh(q[h]+enc_k[b,s,h]) (LDS) ----
    {
      float pacc = 0.f;
      #pragma unroll
      for(int i = 0; i < 8; i++){
        bf16x8 e8 = *(const bf16x8*)(ek_l + ((wv*8 + i) << 9) + lane*8);
        const int kb = i*32 + g2*8;
        #pragma unroll
        for(int j = 0; j < 8; j++){
          float ev = b2f((unsigned short)e8[j]);
          pacc = fmaf(vw_sh[kb + j], ftanh(qgh_sh[kb + j] + ev), pacc);
        }
      }
      pacc += __shfl_xor(pacc, 1); pacc += __shfl_xor(pacc, 2);
      if(g2 == 0) sc_sh[s2] = pacc + vb0;
    }
    __syncthreads();

    // ---- softmax over S=128 (wave 0, redundant both halves) ----
    if(tid < 64){
      float v0 = sc_sh[tid], v1 = sc_sh[tid + 64];
      float m = fmaxf(v0, v1);
      #pragma unroll
      for(int off = 1; off < 64; off <<= 1) m = fmaxf(m, __shfl_xor(m, off));
      float e0 = __expf(v0 - m), e1 = __expf(v1 - m);
      float sm = e0 + e1;
      #pragma unroll
      for(int off = 1; off < 64; off <<= 1) sm += __shfl_xor(sm, off);
      float inv = frcp(sm);
      float w0 = e0*inv, w1 = e1*inv;
      w_sh[tid] = w0; w_sh[tid + 64] = w1;
      if(hb == 0){
        float* ao = atts_out + ((size_t)b*Tn + t)*Sn;
        ao[tid] = w0; ao[tid + 64] = w1;
      }
    }
    __syncthreads();

    // prefetch gi_emb own slices (hide latency under phase 3)
    float ge0 = 0.f, ge1 = 0.f, ge2 = 0.f;
    if(tid < 128){
      const float* ge = gi_emb + ((size_t)t*Bn + b)*GIn + hb*128 + tid;
      ge0 = ge[0]; ge1 = ge[256]; ge2 = ge[512];
    }

    // ---- phase 3: own gi_ctx slice (384 cols): LDS 256 (r,z) + regs 128 (n) ----
    {
      const int c3 = tid >> 1, s3 = tid & 1;
      float a3 = 0.f;
      #pragma unroll
      for(int i = 0; i < 8; i++){
        bf16x8 e = *(const bf16x8*)(ew_l + c3*128 + ((((s3 << 3) + i) ^ (c3 & 15)) << 3));
        const float4 wa = *(const float4*)&w_sh[s3*64 + i*8];
        const float4 wb = *(const float4*)&w_sh[s3*64 + i*8 + 4];
        a3 = fmaf(wa.x, b2f((unsigned short)e[0]), a3);
        a3 = fmaf(wa.y, b2f((unsigned short)e[1]), a3);
        a3 = fmaf(wa.z, b2f((unsigned short)e[2]), a3);
        a3 = fmaf(wa.w, b2f((unsigned short)e[3]), a3);
        a3 = fmaf(wb.x, b2f((unsigned short)e[4]), a3);
        a3 = fmaf(wb.y, b2f((unsigned short)e[5]), a3);
        a3 = fmaf(wb.z, b2f((unsigned short)e[6]), a3);
        a3 = fmaf(wb.w, b2f((unsigned short)e[7]), a3);
      }
      a3 += __shfl_xor(a3, 1);
      if(!(tid & 1)) gic_l[c3] = a3;
      // regs part (n-gate cols)
      const float* wq = &w_sh[(tid & 3)*32];
      float r2 = 0.f;
      #pragma unroll
      for(int j = 0; j < 8; j++) r2 = fmaf(wq[j],      b2f((unsigned short)er0[j]), r2);
      #pragma unroll
      for(int j = 0; j < 8; j++) r2 = fmaf(wq[8 + j],  b2f((unsigned short)er1[j]), r2);
      #pragma unroll
      for(int j = 0; j < 8; j++) r2 = fmaf(wq[16 + j], b2f((unsigned short)er2[j]), r2);
      #pragma unroll
      for(int j = 0; j < 8; j++) r2 = fmaf(wq[24 + j], b2f((unsigned short)er3[j]), r2);
      r2 += __shfl_xor(r2, 1); r2 += __shfl_xor(r2, 2);
      if(!(tid & 3)) gic_l[256 + (tid >> 2)] = r2;
    }
    __syncthreads();

    // ---- phase 4: GRU for own j-slice + ship h-slice to partner ----
    if(tid < 128){
      float gr = ge0 + gic_l[tid];
      float gz = ge1 + gic_l[128 + tid];
      float gn = ge2 + gic_l[256 + tid];
      const int jg = hb*128 + tid;
      float r = fsigm(gr + qgh_sh[256 + jg]);
      float z = fsigm(gz + qgh_sh[512 + jg]);
      float n = ftanh(gn + r*qgh_sh[768 + jg]);
      float hn2 = (1.0f - z)*n + z*h_sh[tid];
      h_sh[tid] = hn2;
      const unsigned short hb16 = f2bu(hn2);
      h_b16[jg] = (short)hb16;
      h_all[((size_t)t*Bn + b)*Hn + jg] = __float2bfloat16(hn2);
      if(t == Tn-1) hfin_out[b*Hn + jg] = hn2;
      if(t < Tn-1){
        float hnx = __shfl_down(hn2, 1);
        if(!(tid & 1)){
          unsigned int u = (unsigned int)hb16 | ((unsigned int)f2bu(hnx) << 16);
          st_ag_u(&hbuf[((size_t)(par*32 + p)*2 + hb)*64 + (tid >> 1)], u);
        }
      }
    }
    __syncthreads();   // drains hbuf stores (vmcnt 0) + h_b16 own slice visible

    if(t < Tn-1){
      if(tid == 0){
        __hip_atomic_store(&hflag[p*2 + hb], (unsigned)(t + 1), __ATOMIC_RELEASE, AGENT);
        long cnt = 0;
        while(__hip_atomic_load(&hflag[p*2 + (hb^1)], __ATOMIC_ACQUIRE, AGENT) < (unsigned)(t + 1)
              && ++cnt < 10000000L){}
      }
      __syncthreads();
      if(tid < 64){
        unsigned int u = ld_ag_u(&hbuf[((size_t)(par*32 + p)*2 + (hb^1))*64 + tid]);
        ((unsigned int*)h_b16)[(hb^1)*64 + tid] = u;
      }
      __syncthreads();
    }
  }
}

// ---------------- deferred logits GEMM: 256x256 tiles, 8 waves ----------------
__global__ __launch_bounds__(512, 2) void k_logits2(
    const short* __restrict__ h_all, const short* __restrict__ w_bf,
    const float* __restrict__ out_b,
    float* __restrict__ pmax, float* __restrict__ psum,
    const float* __restrict__ lse, float* __restrict__ dec_out,
    int pass)
{
  const int tid = threadIdx.x;
  const int wave = tid >> 6, lane = tid & 63;
  const int lr = lane & 15, lg = lane >> 4;
  const int wm = wave >> 2, wn = wave & 3;
  const int n0 = blockIdx.x*256 + wn*64;
  const int m0 = blockIdx.y*256 + wm*128;
  f32x4 acc[8][4];
  #pragma unroll
  for(int mt = 0; mt < 8; mt++)
    #pragma unroll
    for(int nt = 0; nt < 4; nt++) acc[mt][nt] = (f32x4){0.f,0.f,0.f,0.f};
  #pragma unroll
  for(int kk = 0; kk < 8; kk++){
    bf16x8 am[8], bn[4];
    #pragma unroll
    for(int mt = 0; mt < 8; mt++){
      int row = m0 + mt*16 + lr; row = row < 3200 ? row : 3199;
      am[mt] = *(const bf16x8*)(h_all + (size_t)row*Hn + kk*32 + lg*8);
    }
    #pragma unroll
    for(int nt = 0; nt < 4; nt++)
      bn[nt] = *(const bf16x8*)(w_bf + (size_t)(n0 + nt*16 + lr)*Hn + kk*32 + lg*8);
    #pragma unroll
    for(int mt = 0; mt < 8; mt++)
      #pragma unroll
      for(int nt = 0; nt < 4; nt++)
        acc[mt][nt] = __builtin_amdgcn_mfma_f32_16x16x32_bf16(am[mt], bn[nt], acc[mt][nt], 0, 0, 0);
  }
  float bias[4];
  #pragma unroll
  for(int nt = 0; nt < 4; nt++) bias[nt] = out_b[n0 + nt*16 + lr];

  if(pass == 0){
    __shared__ float pm_l[256][4];
    __shared__ float ps_l[256][4];
    #pragma unroll
    for(int mt = 0; mt < 8; mt++){
      #pragma unroll
      for(int i = 0; i < 4; i++){
        float v0 = acc[mt][0][i] + bias[0], v1 = acc[mt][1][i] + bias[1];
        float v2 = acc[mt][2][i] + bias[2], v3 = acc[mt][3][i] + bias[3];
        float m = fmaxf(fmaxf(v0, v1), fmaxf(v2, v3));
        m = fmaxf(m, __shfl_xor(m, 1)); m = fmaxf(m, __shfl_xor(m, 2));
        m = fmaxf(m, __shfl_xor(m, 4)); m = fmaxf(m, __shfl_xor(m, 8));
        float s = __expf(v0 - m) + __expf(v1 - m) + __expf(v2 - m) + __expf(v3 - m);
        s += __shfl_xor(s, 1); s += __shfl_xor(s, 2);
        s += __shfl_xor(s, 4); s += __shfl_xor(s, 8);
        if(lr == 0){
          const int rl = wm*128 + mt*16 + lg*4 + i;
          pm_l[rl][wn] = m; ps_l[rl][wn] = s;
        }
      }
    }
    __syncthreads();
    if(tid < 256){
      const int rg = blockIdx.y*256 + tid;
      if(rg < 3200){
        float m = fmaxf(fmaxf(pm_l[tid][0], pm_l[tid][1]), fmaxf(pm_l[tid][2], pm_l[tid][3]));
        float s = ps_l[tid][0]*__expf(pm_l[tid][0] - m) + ps_l[tid][1]*__expf(pm_l[tid][1] - m)
                + ps_l[tid][2]*__expf(pm_l[tid][2] - m) + ps_l[tid][3]*__expf(pm_l[tid][3] - m);
        pmax[(size_t)blockIdx.x*3200 + rg] = m;
        psum[(size_t)blockIdx.x*3200 + rg] = s;
      }
    }
  } else {
    #pragma unroll
    for(int mt = 0; mt < 8; mt++){
      #pragma unroll
      for(int i = 0; i < 4; i++){
        const int rg = blockIdx.y*256 + wm*128 + mt*16 + lg*4 + i;
        if(rg < 3200){
          const float l = lse[rg];
          const int bb = rg & 31, tt2 = rg >> 5;
          float* dst = dec_out + (size_t)bb*((size_t)Tn*Vn) + (size_t)tt2*Vn + n0;
          dst[ 0 + lr] = acc[mt][0][i] + bias[0] - l;
          dst[16 + lr] = acc[mt][1][i] + bias[1] - l;
          dst[32 + lr] = acc[mt][2][i] + bias[2] - l;
          dst[48 + lr] = acc[mt][3][i] + bias[3] - l;
        }
      }
    }
  }
}

__global__ __launch_bounds__(256) void k_lse(const float* __restrict__ pmax,
    const float* __restrict__ psum, float* __restrict__ lse)
{
  const int row = blockIdx.x*256 + threadIdx.x;
  if(row >= Tn*Bn) return;
  float m = -3.0e38f;
  for(int c = 0; c < 125; c++) m = fmaxf(m, pmax[(size_t)c*3200 + row]);
  float s = 0.f;
  for(int c = 0; c < 125; c++)
    s += psum[(size_t)c*3200 + row] * __expf(pmax[(size_t)c*3200 + row] - m);
  lse[row] = m + __logf(s);
}

// ---------------- launch ----------------
extern "C" void kernel_launch(void* const* d_in, const int* in_sizes, int n_in,
                              void* d_out, int out_size, void* d_ws, size_t ws_size,
                              hipStream_t stream)
{
  const float* enc_outputs = (const float*)d_in[0];
  const float* enc_hidden  = (const float*)d_in[1];
  const int*   target      = (const int*)d_in[2];
  const float* embedding   = (const float*)d_in[3];
  const float* Qw   = (const float*)d_in[4];
  const float* Qb   = (const float*)d_in[5];
  const float* Kw   = (const float*)d_in[6];
  const float* Kb   = (const float*)d_in[7];
  const float* Vw   = (const float*)d_in[8];
  const float* Vb   = (const float*)d_in[9];
  const float* W_ih = (const float*)d_in[10];
  const float* W_hh = (const float*)d_in[11];
  const float* b_ih = (const float*)d_in[12];
  const float* b_hh = (const float*)d_in[13];
  const float* out_w = (const float*)d_in[14];
  const float* out_b = (const float*)d_in[15];

  float* dec  = (float*)d_out;                       // (B,T,V) = 102,400,000 f32
  float* hfin = dec + (size_t)Bn*Tn*Vn;              // (1,B,H)
  float* atts = hfin + Bn*Hn;                        // (B,T,S)

  // Scratch inside dec region (fully consumed before final pass overwrites):
  unsigned short* enc_kb16 = (unsigned short*)(dec);            // 524,288 f32 slots
  unsigned short* ekP      = (unsigned short*)(dec + 524288);   // 524,288
  unsigned short* encW2P   = (unsigned short*)(dec + 1048576);  // 1,572,864
  float* gi_emb = dec + 2621440;                                // 2,457,600
  float* W_ihT  = dec + 5079040;                                // 393,216
  float* KwT    = dec + 5472256;                                // 65,536
  float* pmax   = dec + 5537792;                                // 400,000
  float* psum   = dec + 5937792;                                // 400,000
  unsigned short* W1R = (unsigned short*)(dec + 6337792);       // 163,840 f32 slots (655KB)
  unsigned int* hbuf  = (unsigned int*)(dec + 6501632);         // 8,192 uint
  unsigned int* hflag = (unsigned int*)(dec + 6509824);         // 64 uint (ends 6,509,888)

  // ws: lse + h_all(bf16) + out_w(bf16)
  float* wsf = (float*)d_ws;
  float* lse = wsf;
  __hip_bfloat16* h_all = (__hip_bfloat16*)(wsf + 3200);
  __hip_bfloat16* w_bf  = h_all + (size_t)Tn*Bn*Hn;

  // prep
  k_tr     <<<dim3(8, 8),   dim3(256), 0, stream>>>(Kw, KwT, 256, 256);
  k_tr     <<<dim3(16, 24), dim3(256), 0, stream>>>(W_ih, W_ihT, 768, 512);
  k_packW1R<<<dim3(160),    dim3(256), 0, stream>>>(Qw, W_hh, W1R);
  k_cvt    <<<dim3((Vn*Hn)/1024), dim3(256), 0, stream>>>(out_w, w_bf, Vn*Hn);
  k_enc2   <<<dim3(256), dim3(256), 0, stream>>>(enc_outputs, KwT, Kb, enc_kb16);
  k_packEk <<<dim3(512), dim3(256), 0, stream>>>(enc_kb16, ekP);
  k_encW2b <<<dim3(256), dim3(768), 0, stream>>>(enc_outputs, W_ihT, encW2P);
  k_giemb2 <<<dim3(200), dim3(768), 0, stream>>>(target, embedding, W_ihT, b_ih, gi_emb);

  // reset pair flags (stream-ordered before k_loop5)
  hipMemsetAsync((void*)hflag, 0, 64*sizeof(unsigned int), stream);

  // recurrence: 64 co-resident blocks (2 per batch row, j-split)
  k_loop5 <<<dim3(64), dim3(512), 0, stream>>>(enc_hidden, ekP, encW2P, W1R,
            Qb, b_hh, Vw, Vb, gi_emb, h_all, atts, hfin, hbuf, hflag);

  // logits + log_softmax
  k_logits2<<<dim3(125, 13), dim3(512), 0, stream>>>(
            (const short*)h_all, (const short*)w_bf, out_b,
            pmax, psum, (const float*)nullptr, (float*)nullptr, 0);
  k_lse    <<<dim3(13), dim3(256), 0, stream>>>(pmax, psum, lse);
  k_logits2<<<dim3(125, 13), dim3(512), 0, stream>>>(
            (const short*)h_all, (const short*)w_bf, out_b,
            (float*)nullptr, (float*)nullptr, lse, dec, 1);
}